// Round 5
// baseline (537.762 us; speedup 1.0000x reference)
//
#include <hip/hip_runtime.h>
#include <math.h>

// B=2, H=16, S=2048, DK=64
#define S_LEN 2048
#define NCH   32          // S/64 chunks
#define N_BH  32

typedef short bf16x8 __attribute__((ext_vector_type(8)));
typedef float f32x4  __attribute__((ext_vector_type(4)));
typedef unsigned short u16;
typedef unsigned long long u64;

#define MFMA32(a,b,c) __builtin_amdgcn_mfma_f32_16x16x32_bf16((a),(b),(c),0,0,0)

// (1/sqrt(64)) * log2(e): scores in log2 units; exp2f = one v_exp_f32.
#define SC        0.18033688011112042f
// masked score in log2 units: exp2(-30)=9.3e-10 (negligible vs unmasked;
// a fully-masked column degrades to EXACT uniform 1/2048).
#define MASKED_L2 (-30.0f)

__device__ __forceinline__ u16 f2bf_rne(float x) {
  unsigned u = __float_as_uint(x);
  return (u16)((u + 0x7FFF + ((u >> 16) & 1)) >> 16);
}
// hi = bit-truncation, lo = RNE of residual; combined repr error ~2^-17
__device__ __forceinline__ void bfsplit(float x, u16& h, u16& l) {
  unsigned u = __float_as_uint(x);
  h = (u16)(u >> 16);
  float hf = __uint_as_float(u & 0xFFFF0000u);
  l = f2bf_rne(x - hf);
}

// ---------------------------------------------------------------------------
// Pass 0: bit-pack the mask. word (row, wc) = ballot over k = wc*64 + lane.
// ---------------------------------------------------------------------------
__global__ __launch_bounds__(256) void pack_mask(
    const int* __restrict__ mask, u64* __restrict__ bits) {
  const int word = blockIdx.x * 4 + (threadIdx.x >> 6);
  const int lane = threadIdx.x & 63;
  const int row = word >> 5, wc = word & 31;
  int m = mask[(size_t)row * S_LEN + wc * 64 + lane];
  u64 b = __ballot(m != 0);
  if (lane == 0) bits[word] = b;
}

// ---------------------------------------------------------------------------
// prep_split: x -> (hi, lo) bf16 planes, optional scale. One-shot, coalesced.
// ---------------------------------------------------------------------------
__global__ __launch_bounds__(256) void prep_split(
    const float* __restrict__ src, u16* __restrict__ dh,
    u16* __restrict__ dl, float scale) {
  const size_t i = ((size_t)blockIdx.x * 256 + threadIdx.x) * 4;
  float4 x = *(const float4*)(src + i);
  float xs[4] = {x.x, x.y, x.z, x.w};
  u16 h[4], l[4];
#pragma unroll
  for (int e = 0; e < 4; ++e) bfsplit(xs[e] * scale, h[e], l[e]);
  *(ushort4*)(dh + i) = make_ushort4(h[0], h[1], h[2], h[3]);
  *(ushort4*)(dl + i) = make_ushort4(l[0], l[1], l[2], l[3]);
}

// ---------------------------------------------------------------------------
// prep_w: wT[bh][d][k] = bf16(il[k] * V[bh][k][d])  (64x64 tile transpose)
// ---------------------------------------------------------------------------
__global__ __launch_bounds__(256) void prep_w(
    const float* __restrict__ V, const float* __restrict__ il,
    u16* __restrict__ wT) {
  __shared__ u16 t_s[64 * 72];   // stride 72: rows 16B-aligned, banks spread
  const int tid = threadIdx.x;
  const int kc = blockIdx.x, bh = blockIdx.y;
  {
    const int k = tid >> 2, dblk = (tid & 3) * 16;
    const float ilk = il[(size_t)bh * S_LEN + kc * 64 + k];
    const float* vb = V + ((size_t)bh * S_LEN + kc * 64 + k) * 64 + dblk;
#pragma unroll
    for (int u = 0; u < 4; ++u) {
      float4 x = *(const float4*)(vb + u * 4);
      float xs[4] = {x.x, x.y, x.z, x.w};
#pragma unroll
      for (int e = 0; e < 4; ++e)
        t_s[(dblk + u * 4 + e) * 72 + k] = f2bf_rne(xs[e] * ilk);
    }
  }
  __syncthreads();
  const int d = tid >> 2, kblk = (tid & 3) * 16;
  u16* dst = wT + ((size_t)bh * 64 + d) * S_LEN + kc * 64 + kblk;
#pragma unroll
  for (int u = 0; u < 2; ++u) {
    bf16x8 row = *(const bf16x8*)(t_s + d * 72 + kblk + u * 8);
    *(bf16x8*)(dst + u * 8) = row;
  }
}

// ---------------------------------------------------------------------------
// passA_fast: il[k] = 1 / sum_q exp2(s~[q,k]). Swapped MFMA (A=K, B=Q).
// 512 thr / 8 waves; wave owns 32 k (2 kt tiles, frags in regs from ws);
// block covers 256 k; streams all q 16 rows/step from the split planes.
// ZERO LDS, ZERO barriers, ZERO conversion VALU.
// ---------------------------------------------------------------------------
__global__ __launch_bounds__(512) void passA_fast(
    const u16* __restrict__ qh, const u16* __restrict__ ql,
    const u16* __restrict__ kh, const u16* __restrict__ kl,
    const u64* __restrict__ mbits, float* __restrict__ il_out) {
  const int tid = threadIdx.x;
  const int lane = tid & 63;
  const int w = tid >> 6;          // 0..7
  const int c = lane & 15;
  const int g = lane >> 4;
  const int kc0 = blockIdx.x * 256;
  const int bh = blockIdx.y;

  const u16* qhb = qh + (size_t)bh * S_LEN * 64;
  const u16* qlb = ql + (size_t)bh * S_LEN * 64;
  const u16* khb = kh + (size_t)bh * S_LEN * 64;
  const u16* klb = kl + (size_t)bh * S_LEN * 64;

  bf16x8 kah[2][2], kal[2][2];     // [t][h]
#pragma unroll
  for (int t = 0; t < 2; ++t) {
    const int krow = kc0 + w * 32 + t * 16 + c;
#pragma unroll
    for (int h = 0; h < 2; ++h) {
      kah[t][h] = *(const bf16x8*)(khb + (size_t)krow * 64 + h * 32 + g * 8);
      kal[t][h] = *(const bf16x8*)(klb + (size_t)krow * 64 + h * 32 + g * 8);
    }
  }

  float lp[2][4] = {{0.f}};
  const int word = blockIdx.x * 4 + (w >> 1);
  const int sh0 = (w & 1) * 32;

  for (int qs = 0; qs < S_LEN / 16; ++qs) {
    const int qrow = qs * 16 + c;
    bf16x8 qbh_[2], qbl_[2];
#pragma unroll
    for (int h = 0; h < 2; ++h) {
      qbh_[h] = *(const bf16x8*)(qhb + (size_t)qrow * 64 + h * 32 + g * 8);
      qbl_[h] = *(const bf16x8*)(qlb + (size_t)qrow * 64 + h * 32 + g * 8);
    }
    const u64 mw = mbits[(size_t)qrow * NCH + word];
#pragma unroll
    for (int t = 0; t < 2; ++t) {
      f32x4 acc = {0.f, 0.f, 0.f, 0.f};
#pragma unroll
      for (int h = 0; h < 2; ++h) {     // IDENTICAL order in pass C
        acc = MFMA32(kah[t][h], qbh_[h], acc);
        acc = MFMA32(kal[t][h], qbh_[h], acc);
        acc = MFMA32(kah[t][h], qbl_[h], acc);
      }
      const unsigned nib = (unsigned)(mw >> (sh0 + t * 16 + g * 4)) & 0xFu;
#pragma unroll
      for (int r = 0; r < 4; ++r) {
        float s = ((nib >> r) & 1) ? MASKED_L2 : acc[r];
        lp[t][r] += exp2f(s);
      }
    }
  }
  // reduce over the 16 c-lanes of each g-group
#pragma unroll
  for (int off = 1; off < 16; off <<= 1)
#pragma unroll
    for (int t = 0; t < 2; ++t)
#pragma unroll
      for (int r = 0; r < 4; ++r) lp[t][r] += __shfl_xor(lp[t][r], off, 64);
  if (c == 0) {
#pragma unroll
    for (int t = 0; t < 2; ++t) {
      float4 o = {1.f / lp[t][0], 1.f / lp[t][1],
                  1.f / lp[t][2], 1.f / lp[t][3]};
      *(float4*)(il_out + (size_t)bh * S_LEN + kc0 + w * 32 + t * 16 + g * 4) = o;
    }
  }
}

// ---------------------------------------------------------------------------
// passC_fast: out[q,d] = sum_k exp2(s~[q,k]) * wT[d,k].
// K/Q/W frags all register-loaded from ws planes (L1/L2-hot, shared across
// waves). LDS = per-wave P tile only; ZERO barriers.
// ---------------------------------------------------------------------------
__global__ __launch_bounds__(256) void passC_fast(
    const u16* __restrict__ qh, const u16* __restrict__ ql,
    const u16* __restrict__ kh, const u16* __restrict__ kl,
    const u16* __restrict__ wT, const u64* __restrict__ mbits,
    float* __restrict__ out) {
  __shared__ u16 p_s[4 * 1024];    // per-wave [16 q][64 k] bf16, swizzled

  const int tid = threadIdx.x;
  const int lane = tid & 63;
  const int w = tid >> 6;
  const int c = lane & 15;
  const int g = lane >> 4;
  const int qc = blockIdx.x;
  const int bh = blockIdx.y;

  const u16* qhb = qh + (size_t)bh * S_LEN * 64;
  const u16* qlb = ql + (size_t)bh * S_LEN * 64;
  const u16* khb = kh + (size_t)bh * S_LEN * 64;
  const u16* klb = kl + (size_t)bh * S_LEN * 64;
  const u16* wTb = wT + (size_t)bh * 64 * S_LEN;

  const int qrow = qc * 64 + w * 16 + c;
  bf16x8 qbh_[2], qbl_[2];
#pragma unroll
  for (int h = 0; h < 2; ++h) {
    qbh_[h] = *(const bf16x8*)(qhb + (size_t)qrow * 64 + h * 32 + g * 8);
    qbl_[h] = *(const bf16x8*)(qlb + (size_t)qrow * 64 + h * 32 + g * 8);
  }

  f32x4 oacc[4];
#pragma unroll
  for (int dt = 0; dt < 4; ++dt) oacc[dt] = (f32x4){0.f, 0.f, 0.f, 0.f};

  const int swc = (c & 7) << 3;
  const int pbase = w * 1024 + c * 64;

  for (int kc = 0; kc < NCH; ++kc) {
    const u64 mw = mbits[(size_t)qrow * NCH + kc];

    // QK^T + mask + exp2 -> P (per-wave LDS tile; same-wave RAW only)
#pragma unroll
    for (int kt = 0; kt < 4; ++kt) {
      const int krow = kc * 64 + kt * 16 + c;
      bf16x8 akh[2], akl[2];
#pragma unroll
      for (int h = 0; h < 2; ++h) {
        akh[h] = *(const bf16x8*)(khb + (size_t)krow * 64 + h * 32 + g * 8);
        akl[h] = *(const bf16x8*)(klb + (size_t)krow * 64 + h * 32 + g * 8);
      }
      f32x4 acc = {0.f, 0.f, 0.f, 0.f};
#pragma unroll
      for (int h = 0; h < 2; ++h) {     // IDENTICAL order to pass A
        acc = MFMA32(akh[h], qbh_[h], acc);
        acc = MFMA32(akl[h], qbh_[h], acc);
        acc = MFMA32(akh[h], qbl_[h], acc);
      }
      const unsigned nib = (unsigned)(mw >> (kt * 16 + g * 4)) & 0xFu;
      u16 pb[4];
#pragma unroll
      for (int r = 0; r < 4; ++r) {
        const float s = ((nib >> r) & 1) ? MASKED_L2 : acc[r];
        pb[r] = f2bf_rne(exp2f(s));
      }
      *(ushort4*)(p_s + pbase + ((kt * 16 + g * 4) ^ swc)) =
          make_ushort4(pb[0], pb[1], pb[2], pb[3]);
    }

    // PV: oacc[dt] += wT[16dt.., k-slice] * P[k-slice, q]  (2 slices of 32)
#pragma unroll
    for (int s = 0; s < 2; ++s) {
      bf16x8 pb8 = *(const bf16x8*)(p_s + pbase + ((s * 32 + g * 8) ^ swc));
#pragma unroll
      for (int dt = 0; dt < 4; ++dt) {
        bf16x8 av = *(const bf16x8*)(wTb + (size_t)(dt * 16 + c) * S_LEN
                                     + kc * 64 + s * 32 + g * 8);
        oacc[dt] = MFMA32(av, pb8, oacc[dt]);
      }
    }
  }

  // epilogue: lane (c,g) owns row q = qrow, cols d = 16dt+4g+r
  float* ob = out + (size_t)((size_t)bh * S_LEN + qrow) * 64;
#pragma unroll
  for (int dt = 0; dt < 4; ++dt) {
    float4 o = {oacc[dt][0], oacc[dt][1], oacc[dt][2], oacc[dt][3]};
    *(float4*)(ob + dt * 16 + g * 4) = o;
  }
}

// ===========================================================================
// FALLBACK (round-4 proven kernels) — used when ws_size is too small.
// ===========================================================================
__global__ __launch_bounds__(256) void passA_colsum(
    const float* __restrict__ Q, const float* __restrict__ K,
    const u64* __restrict__ mbits, float* __restrict__ il_out) {
  const int tid = threadIdx.x;
  const int lane = tid & 63;
  const int w = tid >> 6;
  const int c = lane & 15;
  const int g = lane >> 4;
  const int kc = blockIdx.x;
  const int bh = blockIdx.y;

  const float* Qb = Q + (size_t)bh * S_LEN * 64;
  const float* Kb = K + (size_t)bh * S_LEN * 64;

  bf16x8 kah[2], kal[2];
  {
    const int krow = kc * 64 + w * 16 + c;
#pragma unroll
    for (int h = 0; h < 2; ++h) {
      const float* src = Kb + (size_t)krow * 64 + h * 32 + g * 8;
      float4 x = *(const float4*)(src);
      float4 y = *(const float4*)(src + 4);
      float xs[8] = {x.x, x.y, x.z, x.w, y.x, y.y, y.z, y.w};
#pragma unroll
      for (int e = 0; e < 8; ++e) {
        u16 hh, ll; bfsplit(xs[e], hh, ll);
        kah[h][e] = (short)hh; kal[h][e] = (short)ll;
      }
    }
  }

  float lp[4] = {0.f, 0.f, 0.f, 0.f};
  const int shift = w * 16 + g * 4;

  for (int qs = 0; qs < S_LEN / 16; ++qs) {
    const int qrow = qs * 16 + c;
    bf16x8 qbh_[2], qbl_[2];
#pragma unroll
    for (int h = 0; h < 2; ++h) {
      const float* src = Qb + (size_t)qrow * 64 + h * 32 + g * 8;
      float4 x = *(const float4*)(src);
      float4 y = *(const float4*)(src + 4);
      float xs[8] = {x.x, x.y, x.z, x.w, y.x, y.y, y.z, y.w};
#pragma unroll
      for (int e = 0; e < 8; ++e) {
        u16 hh, ll; bfsplit(xs[e] * SC, hh, ll);
        qbh_[h][e] = (short)hh; qbl_[h][e] = (short)ll;
      }
    }
    f32x4 acc = {0.f, 0.f, 0.f, 0.f};
#pragma unroll
    for (int h = 0; h < 2; ++h) {
      acc = MFMA32(kah[h], qbh_[h], acc);
      acc = MFMA32(kal[h], qbh_[h], acc);
      acc = MFMA32(kah[h], qbl_[h], acc);
    }
    u64 mw = mbits[(size_t)qrow * NCH + kc];
    unsigned nib = (unsigned)(mw >> shift) & 0xFu;
#pragma unroll
    for (int r = 0; r < 4; ++r) {
      float s = ((nib >> r) & 1) ? MASKED_L2 : acc[r];
      lp[r] += exp2f(s);
    }
  }
#pragma unroll
  for (int off = 1; off < 16; off <<= 1)
#pragma unroll
    for (int r = 0; r < 4; ++r) lp[r] += __shfl_xor(lp[r], off, 64);
  if (c == 0) {
    float4 o = {1.f / lp[0], 1.f / lp[1], 1.f / lp[2], 1.f / lp[3]};
    *(float4*)(il_out + (size_t)bh * S_LEN + kc * 64 + w * 16 + g * 4) = o;
  }
}

__global__ __launch_bounds__(256) void passC_out(
    const float* __restrict__ Q, const float* __restrict__ K,
    const float* __restrict__ V, const u64* __restrict__ mbits,
    const float* __restrict__ il_in, float* __restrict__ out) {
  __shared__ u16 kh_s[4096];
  __shared__ u16 kl_s[4096];
  __shared__ u16 vt_s[4096];
  __shared__ u16 p_s[4096];

  const int tid = threadIdx.x;
  const int lane = tid & 63;
  const int w = tid >> 6;
  const int c = lane & 15;
  const int g = lane >> 4;
  const int qc = blockIdx.x;
  const int bh = blockIdx.y;

  const float* Qb = Q + (size_t)bh * S_LEN * 64;
  const float* Kb = K + (size_t)bh * S_LEN * 64;
  const float* Vb = V + (size_t)bh * S_LEN * 64;

  bf16x8 qbh_[2], qbl_[2];
  {
    const int qrow = qc * 64 + w * 16 + c;
#pragma unroll
    for (int h = 0; h < 2; ++h) {
      const float* src = Qb + (size_t)qrow * 64 + h * 32 + g * 8;
      float4 x = *(const float4*)(src);
      float4 y = *(const float4*)(src + 4);
      float xs[8] = {x.x, x.y, x.z, x.w, y.x, y.y, y.z, y.w};
#pragma unroll
      for (int e = 0; e < 8; ++e) {
        u16 hh, ll; bfsplit(xs[e] * SC, hh, ll);
        qbh_[h][e] = (short)hh; qbl_[h][e] = (short)ll;
      }
    }
  }

  f32x4 oacc[4];
#pragma unroll
  for (int dt = 0; dt < 4; ++dt) oacc[dt] = (f32x4){0.f, 0.f, 0.f, 0.f};

  const int slot = tid & 15, r0 = tid >> 4;
  const int kv = tid & 63, dblk = tid >> 6;
  const int swc = (c & 7) << 3;
  const int pbase = w * 1024 + c * 64;

  for (int kc = 0; kc < NCH; ++kc) {
    __syncthreads();
#pragma unroll
    for (int p = 0; p < 4; ++p) {
      const int row = p * 16 + r0;
      float4 kx = *(const float4*)(Kb + (size_t)(kc * 64 + row) * 64 + slot * 4);
      float xs[4] = {kx.x, kx.y, kx.z, kx.w};
      u16 ha[4], la[4];
#pragma unroll
      for (int e = 0; e < 4; ++e) bfsplit(xs[e], ha[e], la[e]);
      const int idx = row * 64 + ((slot * 4) ^ ((row & 7) << 3));
      *(ushort4*)(kh_s + idx) = make_ushort4(ha[0], ha[1], ha[2], ha[3]);
      *(ushort4*)(kl_s + idx) = make_ushort4(la[0], la[1], la[2], la[3]);
    }
    {
      const float ilk = il_in[(size_t)bh * S_LEN + kc * 64 + kv];
#pragma unroll
      for (int u = 0; u < 4; ++u) {
        float4 vv = *(const float4*)(Vb + (size_t)(kc * 64 + kv) * 64 + dblk * 16 + u * 4);
        float xs[4] = {vv.x, vv.y, vv.z, vv.w};
#pragma unroll
        for (int e = 0; e < 4; ++e) {
          const int d = dblk * 16 + u * 4 + e;
          vt_s[d * 64 + (kv ^ ((d & 7) << 3))] = f2bf_rne(xs[e] * ilk);
        }
      }
    }
    __syncthreads();

    const u64 mw = mbits[(size_t)(qc * 64 + w * 16 + c) * NCH + kc];

#pragma unroll
    for (int kt = 0; kt < 4; ++kt) {
      const int kbase = (16 * kt + c) * 64;
      bf16x8 akh[2], akl[2];
#pragma unroll
      for (int h = 0; h < 2; ++h) {
        const int off = (h * 32 + g * 8) ^ swc;
        akh[h] = *(const bf16x8*)(kh_s + kbase + off);
        akl[h] = *(const bf16x8*)(kl_s + kbase + off);
      }
      f32x4 acc = {0.f, 0.f, 0.f, 0.f};
#pragma unroll
      for (int h = 0; h < 2; ++h) {
        acc = MFMA32(akh[h], qbh_[h], acc);
        acc = MFMA32(akl[h], qbh_[h], acc);
        acc = MFMA32(akh[h], qbl_[h], acc);
      }
      const unsigned nib = (unsigned)(mw >> (kt * 16 + g * 4)) & 0xFu;
      u16 pb[4];
#pragma unroll
      for (int r = 0; r < 4; ++r) {
        const float s = ((nib >> r) & 1) ? MASKED_L2 : acc[r];
        pb[r] = f2bf_rne(exp2f(s));
      }
      *(ushort4*)(p_s + pbase + ((kt * 16 + g * 4) ^ swc)) =
          make_ushort4(pb[0], pb[1], pb[2], pb[3]);
    }
    __syncthreads();

#pragma unroll
    for (int s = 0; s < 2; ++s) {
      const int koff = (s * 32 + 8 * g) ^ swc;
      bf16x8 pb8 = *(const bf16x8*)(p_s + pbase + koff);
#pragma unroll
      for (int dt = 0; dt < 4; ++dt) {
        bf16x8 av = *(const bf16x8*)(vt_s + (16 * dt + c) * 64 + koff);
        oacc[dt] = MFMA32(av, pb8, oacc[dt]);
      }
    }
  }

  float* ob = out + ((size_t)bh * S_LEN + qc * 64 + w * 16 + c) * 64;
#pragma unroll
  for (int dt = 0; dt < 4; ++dt) {
    float4 o = {oacc[dt][0], oacc[dt][1], oacc[dt][2], oacc[dt][3]};
    *(float4*)(ob + dt * 16 + g * 4) = o;
  }
}

extern "C" void kernel_launch(void* const* d_in, const int* in_sizes, int n_in,
                              void* d_out, int out_size, void* d_ws, size_t ws_size,
                              hipStream_t stream) {
  (void)in_sizes; (void)n_in; (void)out_size;
  const float* q = (const float*)d_in[0];
  const float* k = (const float*)d_in[1];
  const float* v = (const float*)d_in[2];
  const int* mask = (const int*)d_in[3];
  float* out = (float*)d_out;

  // ws layout: mbits (512KB) | il (256KB) | qh | ql | kh | kl | wT (bf16 planes)
  u64* mbits = (u64*)d_ws;
  float* il = (float*)((char*)d_ws + 524288);
  const size_t PL = (size_t)N_BH * S_LEN * 64;       // 4,194,304 elems/plane
  u16* qh = (u16*)((char*)d_ws + 786432);
  u16* ql = qh + PL;
  u16* kh = ql + PL;
  u16* kl = kh + PL;
  u16* wT = kl + PL;
  const size_t need = 786432 + 5 * PL * sizeof(u16); // 42,729,472 B

  pack_mask<<<dim3(S_LEN * NCH / 4), 256, 0, stream>>>(mask, mbits);

  if (ws_size >= need) {
    const int nb = (int)(PL / (256 * 4));            // 4096 blocks/plane
    prep_split<<<dim3(nb), 256, 0, stream>>>(q, qh, ql, SC);
    prep_split<<<dim3(nb), 256, 0, stream>>>(k, kh, kl, 1.0f);
    passA_fast<<<dim3(S_LEN / 256, N_BH), 512, 0, stream>>>(
        qh, ql, kh, kl, mbits, il);
    prep_w<<<dim3(NCH, N_BH), 256, 0, stream>>>(v, il, wT);
    passC_fast<<<dim3(NCH, N_BH), 256, 0, stream>>>(
        qh, ql, kh, kl, wT, mbits, out);
  } else {
    dim3 grid(NCH, N_BH);
    passA_colsum<<<grid, 256, 0, stream>>>(q, k, mbits, il);
    passC_out<<<grid, 256, 0, stream>>>(q, k, v, mbits, il, out);
  }
}

// Round 6
// 261.167 us; speedup vs baseline: 2.0591x; 2.0591x over previous
//
#include <hip/hip_runtime.h>
#include <math.h>

// B=2, H=16, S=2048, DK=64
#define S_LEN 2048
#define NCH   32          // S/64 chunks
#define N_BH  32

typedef short bf16x8 __attribute__((ext_vector_type(8)));
typedef float f32x4  __attribute__((ext_vector_type(4)));
typedef unsigned short u16;
typedef unsigned short u16x8 __attribute__((ext_vector_type(8)));
typedef unsigned long long u64;

#define MFMA32(a,b,c) __builtin_amdgcn_mfma_f32_16x16x32_bf16((a),(b),(c),0,0,0)
#define EXP2(x) __builtin_amdgcn_exp2f(x)

// (1/sqrt(64)) * log2(e): scores in log2 units; exp2 = one v_exp_f32.
#define SC        0.18033688011112042f
// masked score in log2 units: exp2(-30)=9.3e-10 (negligible vs unmasked;
// a fully-masked column degrades to EXACT uniform 1/2048).
#define MASKED_L2 (-30.0f)

__device__ __forceinline__ u16 f2bf_rne(float x) {
  unsigned u = __float_as_uint(x);
  return (u16)((u + 0x7FFF + ((u >> 16) & 1)) >> 16);
}
// hi = bit-truncation, lo = RNE of residual; combined repr error ~2^-17
__device__ __forceinline__ void bfsplit(float x, u16& h, u16& l) {
  unsigned u = __float_as_uint(x);
  h = (u16)(u >> 16);
  float hf = __uint_as_float(u & 0xFFFF0000u);
  l = f2bf_rne(x - hf);
}

// ---------------------------------------------------------------------------
// pack_mask: word (row, wc) = ballot over k = wc*64 + lane.
// ---------------------------------------------------------------------------
__global__ __launch_bounds__(256) void pack_mask(
    const int* __restrict__ mask, u64* __restrict__ bits) {
  const int word = blockIdx.x * 4 + (threadIdx.x >> 6);
  const int lane = threadIdx.x & 63;
  const int row = word >> 5, wc = word & 31;
  int m = mask[(size_t)row * S_LEN + wc * 64 + lane];
  u64 b = __ballot(m != 0);
  if (lane == 0) bits[word] = b;
}

// ---------------------------------------------------------------------------
// prep_q: Q*SC -> (hi, lo) bf16 planes, linear [bh][row][64]. Coalesced.
// ---------------------------------------------------------------------------
__global__ __launch_bounds__(256) void prep_q(
    const float* __restrict__ src, u16* __restrict__ dh, u16* __restrict__ dl) {
  const size_t i = ((size_t)blockIdx.x * 256 + threadIdx.x) * 4;
  float4 x = *(const float4*)(src + i);
  float xs[4] = {x.x, x.y, x.z, x.w};
  u16 h[4], l[4];
#pragma unroll
  for (int e = 0; e < 4; ++e) bfsplit(xs[e] * SC, h[e], l[e]);
  *(ushort4*)(dh + i) = make_ushort4(h[0], h[1], h[2], h[3]);
  *(ushort4*)(dl + i) = make_ushort4(l[0], l[1], l[2], l[3]);
}

// ---------------------------------------------------------------------------
// prep_k: K -> (hi, lo) bf16, stored as SWIZZLED 64x64 tiles
// [bh][kc][ row*64 + (col ^ ((row&7)*8)) ]  -- the exact LDS layout passC
// wants, so passC staging is a pure 16B copy.
// ---------------------------------------------------------------------------
__global__ __launch_bounds__(256) void prep_k(
    const float* __restrict__ K, u16* __restrict__ kh_t, u16* __restrict__ kl_t) {
  __shared__ __align__(16) u16 th[4096];
  __shared__ __align__(16) u16 tl[4096];
  const int tid = threadIdx.x;
  const int kc = blockIdx.x, bh = blockIdx.y;
  const int slot = tid & 15, r0 = tid >> 4;
#pragma unroll
  for (int p = 0; p < 4; ++p) {
    const int row = p * 16 + r0;
    float4 kx = *(const float4*)(K + ((size_t)bh * S_LEN + kc * 64 + row) * 64 + slot * 4);
    float xs[4] = {kx.x, kx.y, kx.z, kx.w};
    u16 ha[4], la[4];
#pragma unroll
    for (int e = 0; e < 4; ++e) bfsplit(xs[e], ha[e], la[e]);
    const int idx = row * 64 + ((slot * 4) ^ ((row & 7) << 3));
    *(ushort4*)(th + idx) = make_ushort4(ha[0], ha[1], ha[2], ha[3]);
    *(ushort4*)(tl + idx) = make_ushort4(la[0], la[1], la[2], la[3]);
  }
  __syncthreads();
  u16* dh = kh_t + ((size_t)bh * NCH + kc) * 4096;
  u16* dl = kl_t + ((size_t)bh * NCH + kc) * 4096;
#pragma unroll
  for (int j = 0; j < 2; ++j) {
    *(u16x8*)(dh + j * 2048 + tid * 8) = *(const u16x8*)(th + j * 2048 + tid * 8);
    *(u16x8*)(dl + j * 2048 + tid * 8) = *(const u16x8*)(tl + j * 2048 + tid * 8);
  }
}

// ---------------------------------------------------------------------------
// prep_w: il[k] = 1/sum(partials); wT[d][k] = bf16(il*V[k][d]) as SWIZZLED
// 64x64 tiles [bh][kc][ d*64 + (k ^ ((d&7)*8)) ].
// ---------------------------------------------------------------------------
__global__ __launch_bounds__(256) void prep_w(
    const float* __restrict__ V, const float* __restrict__ part,
    u16* __restrict__ w_t) {
  __shared__ __align__(16) u16 ts[4096];
  const int tid = threadIdx.x;
  const int kc = blockIdx.x, bh = blockIdx.y;
  const int k = tid >> 2, dblk = (tid & 3) * 16;
  const size_t ko = (size_t)bh * S_LEN + kc * 64 + k;
  const float lsum = part[ko] + part[65536 + ko] + part[131072 + ko] + part[196608 + ko];
  const float ilk = 1.0f / lsum;
  const float* vb = V + ko * 64 + dblk;
#pragma unroll
  for (int u = 0; u < 4; ++u) {
    float4 x = *(const float4*)(vb + u * 4);
    float xs[4] = {x.x, x.y, x.z, x.w};
#pragma unroll
    for (int e = 0; e < 4; ++e) {
      const int d = dblk + u * 4 + e;
      ts[d * 64 + (k ^ ((d & 7) << 3))] = f2bf_rne(xs[e] * ilk);
    }
  }
  __syncthreads();
  u16* dst = w_t + ((size_t)bh * NCH + kc) * 4096;
#pragma unroll
  for (int j = 0; j < 2; ++j)
    *(u16x8*)(dst + j * 2048 + tid * 8) = *(const u16x8*)(ts + j * 2048 + tid * 8);
}

// ---------------------------------------------------------------------------
// passA: partial column sums over one q-quarter.
// Grid (8 kc-blocks, 32 bh, 4 qpart) x 512 thr. Wave owns 32 k (frags in
// regs from swizzled tiles); streams 512 q rows. ZERO LDS/barriers.
// ---------------------------------------------------------------------------
__global__ __launch_bounds__(512) void passA(
    const u16* __restrict__ qh, const u16* __restrict__ ql,
    const u16* __restrict__ kh_t, const u16* __restrict__ kl_t,
    const u64* __restrict__ mbits, float* __restrict__ part) {
  const int tid = threadIdx.x;
  const int lane = tid & 63;
  const int w = tid >> 6;          // 0..7
  const int c = lane & 15;
  const int g = lane >> 4;
  const int bx = blockIdx.x;       // 0..7 (256 k each)
  const int bh = blockIdx.y;
  const int qp = blockIdx.z;       // 0..3 (512 q each)

  const u16* qhb = qh + (size_t)bh * S_LEN * 64;
  const u16* qlb = ql + (size_t)bh * S_LEN * 64;
  const size_t tbase = (size_t)bh * NCH * 4096;

  // K A-frags from swizzled tiles (held in regs for the whole block)
  bf16x8 kah[2][2], kal[2][2];
#pragma unroll
  for (int t = 0; t < 2; ++t) {
    const int rg = w * 32 + t * 16;                // 0..240
    const size_t tb = tbase + (size_t)(bx * 4 + (rg >> 6)) * 4096;
    const int row = (rg & 63) + c;
#pragma unroll
    for (int h = 0; h < 2; ++h) {
      const int off = (h * 32 + g * 8) ^ ((c & 7) << 3);
      kah[t][h] = *(const bf16x8*)(kh_t + tb + row * 64 + off);
      kal[t][h] = *(const bf16x8*)(kl_t + tb + row * 64 + off);
    }
  }

  float lp[2][4] = {{0.f, 0.f, 0.f, 0.f}, {0.f, 0.f, 0.f, 0.f}};
  const int word = bx * 4 + (w >> 1);              // same for t=0,1
  const int sh0 = (w & 1) * 32 + g * 4;

  for (int qs = 0; qs < 32; ++qs) {
    const int qrow = qp * 512 + qs * 16 + c;
    bf16x8 qbh_[2], qbl_[2];
#pragma unroll
    for (int h = 0; h < 2; ++h) {
      qbh_[h] = *(const bf16x8*)(qhb + (size_t)qrow * 64 + h * 32 + g * 8);
      qbl_[h] = *(const bf16x8*)(qlb + (size_t)qrow * 64 + h * 32 + g * 8);
    }
    const u64 mw = mbits[(size_t)qrow * NCH + word];
#pragma unroll
    for (int t = 0; t < 2; ++t) {
      f32x4 acc = {0.f, 0.f, 0.f, 0.f};
#pragma unroll
      for (int h = 0; h < 2; ++h) {     // IDENTICAL order in passC
        acc = MFMA32(kah[t][h], qbh_[h], acc);
        acc = MFMA32(kal[t][h], qbh_[h], acc);
        acc = MFMA32(kah[t][h], qbl_[h], acc);
      }
      const unsigned nib = (unsigned)(mw >> (sh0 + t * 16)) & 0xFu;
#pragma unroll
      for (int r = 0; r < 4; ++r) {
        const float s = ((nib >> r) & 1) ? MASKED_L2 : acc[r];
        lp[t][r] += EXP2(s);
      }
    }
  }
  // reduce over the 16 c-lanes of each g-group
#pragma unroll
  for (int off = 1; off < 16; off <<= 1)
#pragma unroll
    for (int t = 0; t < 2; ++t)
#pragma unroll
      for (int r = 0; r < 4; ++r) lp[t][r] += __shfl_xor(lp[t][r], off, 64);
  if (c == 0) {
#pragma unroll
    for (int t = 0; t < 2; ++t) {
      float4 o = {lp[t][0], lp[t][1], lp[t][2], lp[t][3]};
      *(float4*)(part + (size_t)qp * 65536 + (size_t)bh * S_LEN
                 + bx * 256 + w * 32 + t * 16 + g * 4) = o;
    }
  }
}

// ---------------------------------------------------------------------------
// passC: out[q,d] = sum_k exp2(s~[q,k]) * wT[d,k].
// 4 waves share an LDS-staged chunk {kh|kl|wT} (24KB, pre-swizzled tiles ->
// staging is a pure 16B copy). T14 async-split: next chunk's global loads
// issue before compute, ds_write after the barrier. LDS 32KB total.
// ---------------------------------------------------------------------------
__global__ __launch_bounds__(256) void passC(
    const u16* __restrict__ qh, const u16* __restrict__ ql,
    const u16* __restrict__ kh_t, const u16* __restrict__ kl_t,
    const u16* __restrict__ w_t, const u64* __restrict__ mbits,
    float* __restrict__ out) {
  __shared__ __align__(16) u16 sbuf[12288];   // [kh:4096 | kl:4096 | wT:4096]
  __shared__ __align__(16) u16 p_s[4096];     // per-wave [16 q][64 k], swizzled

  const int tid = threadIdx.x;
  const int lane = tid & 63;
  const int w = tid >> 6;
  const int c = lane & 15;
  const int g = lane >> 4;
  const int qc = blockIdx.x;
  const int bh = blockIdx.y;

  const u16* qhb = qh + (size_t)bh * S_LEN * 64;
  const u16* qlb = ql + (size_t)bh * S_LEN * 64;
  const u16* tb_h = kh_t + (size_t)bh * NCH * 4096;
  const u16* tb_l = kl_t + (size_t)bh * NCH * 4096;
  const u16* tb_w = w_t + (size_t)bh * NCH * 4096;

  const int qrow = qc * 64 + w * 16 + c;
  bf16x8 qbh_[2], qbl_[2];
#pragma unroll
  for (int h = 0; h < 2; ++h) {
    qbh_[h] = *(const bf16x8*)(qhb + (size_t)qrow * 64 + h * 32 + g * 8);
    qbl_[h] = *(const bf16x8*)(qlb + (size_t)qrow * 64 + h * 32 + g * 8);
  }

  f32x4 oacc[4];
#pragma unroll
  for (int dt = 0; dt < 4; ++dt) oacc[dt] = (f32x4){0.f, 0.f, 0.f, 0.f};

  const int swc = (c & 7) << 3;
  const int pbase = w * 1024 + c * 64;
  const int so = tid * 8;                     // staging offset (u16 units)

  // prologue: load chunk 0 into staging regs
  u16x8 stg[6];
#pragma unroll
  for (int j = 0; j < 2; ++j) {
    stg[0 + j] = *(const u16x8*)(tb_h + j * 2048 + so);
    stg[2 + j] = *(const u16x8*)(tb_l + j * 2048 + so);
    stg[4 + j] = *(const u16x8*)(tb_w + j * 2048 + so);
  }

  for (int kc = 0; kc < NCH; ++kc) {
    __syncthreads();                          // prior readers of sbuf done
    // commit staged regs (compiler inserts vmcnt wait here)
#pragma unroll
    for (int j = 0; j < 2; ++j) {
      *(u16x8*)(sbuf + j * 2048 + so) = stg[0 + j];
      *(u16x8*)(sbuf + 4096 + j * 2048 + so) = stg[2 + j];
      *(u16x8*)(sbuf + 8192 + j * 2048 + so) = stg[4 + j];
    }
    __syncthreads();                          // sbuf ready
    // issue next chunk's loads NOW; consumed after next barrier (T14)
    if (kc + 1 < NCH) {
      const size_t nb = (size_t)(kc + 1) * 4096;
#pragma unroll
      for (int j = 0; j < 2; ++j) {
        stg[0 + j] = *(const u16x8*)(tb_h + nb + j * 2048 + so);
        stg[2 + j] = *(const u16x8*)(tb_l + nb + j * 2048 + so);
        stg[4 + j] = *(const u16x8*)(tb_w + nb + j * 2048 + so);
      }
    }

    const u64 mw = mbits[(size_t)qrow * NCH + kc];

    // QK^T + mask + exp2 -> P (per-wave LDS tile)
#pragma unroll
    for (int kt = 0; kt < 4; ++kt) {
      const int kbase = (16 * kt + c) * 64;
      bf16x8 akh[2], akl[2];
#pragma unroll
      for (int h = 0; h < 2; ++h) {
        const int off = (h * 32 + g * 8) ^ swc;
        akh[h] = *(const bf16x8*)(sbuf + kbase + off);
        akl[h] = *(const bf16x8*)(sbuf + 4096 + kbase + off);
      }
      f32x4 acc = {0.f, 0.f, 0.f, 0.f};
#pragma unroll
      for (int h = 0; h < 2; ++h) {     // IDENTICAL order to passA
        acc = MFMA32(akh[h], qbh_[h], acc);
        acc = MFMA32(akl[h], qbh_[h], acc);
        acc = MFMA32(akh[h], qbl_[h], acc);
      }
      const unsigned nib = (unsigned)(mw >> (kt * 16 + g * 4)) & 0xFu;
      u16 pb[4];
#pragma unroll
      for (int r = 0; r < 4; ++r) {
        const float s = ((nib >> r) & 1) ? MASKED_L2 : acc[r];
        pb[r] = f2bf_rne(EXP2(s));
      }
      *(ushort4*)(p_s + pbase + ((kt * 16 + g * 4) ^ swc)) =
          make_ushort4(pb[0], pb[1], pb[2], pb[3]);
    }

    // PV: oacc[dt] += wT[16dt.., k-slice] * P[k-slice, q]  (2 slices of 32)
#pragma unroll
    for (int s2 = 0; s2 < 2; ++s2) {
      const int koff = (s2 * 32 + g * 8) ^ swc;
      bf16x8 pb8 = *(const bf16x8*)(p_s + pbase + koff);
#pragma unroll
      for (int dt = 0; dt < 4; ++dt) {
        bf16x8 av = *(const bf16x8*)(sbuf + 8192 + (16 * dt + c) * 64 + koff);
        oacc[dt] = MFMA32(av, pb8, oacc[dt]);
      }
    }
  }

  // epilogue: lane (c,g) owns row q = qrow, cols d = 16dt+4g+r
  float* ob = out + ((size_t)bh * S_LEN + qrow) * 64;
#pragma unroll
  for (int dt = 0; dt < 4; ++dt) {
    float4 o = {oacc[dt][0], oacc[dt][1], oacc[dt][2], oacc[dt][3]};
    *(float4*)(ob + dt * 16 + g * 4) = o;
  }
}

// ===========================================================================
// FALLBACK (round-4 proven kernels) — used when ws_size is too small.
// ===========================================================================
__global__ __launch_bounds__(256) void passA_colsum(
    const float* __restrict__ Q, const float* __restrict__ K,
    const u64* __restrict__ mbits, float* __restrict__ il_out) {
  const int tid = threadIdx.x;
  const int lane = tid & 63;
  const int w = tid >> 6;
  const int c = lane & 15;
  const int g = lane >> 4;
  const int kc = blockIdx.x;
  const int bh = blockIdx.y;

  const float* Qb = Q + (size_t)bh * S_LEN * 64;
  const float* Kb = K + (size_t)bh * S_LEN * 64;

  bf16x8 kah[2], kal[2];
  {
    const int krow = kc * 64 + w * 16 + c;
#pragma unroll
    for (int h = 0; h < 2; ++h) {
      const float* src = Kb + (size_t)krow * 64 + h * 32 + g * 8;
      float4 x = *(const float4*)(src);
      float4 y = *(const float4*)(src + 4);
      float xs[8] = {x.x, x.y, x.z, x.w, y.x, y.y, y.z, y.w};
#pragma unroll
      for (int e = 0; e < 8; ++e) {
        u16 hh, ll; bfsplit(xs[e], hh, ll);
        kah[h][e] = (short)hh; kal[h][e] = (short)ll;
      }
    }
  }

  float lp[4] = {0.f, 0.f, 0.f, 0.f};
  const int shift = w * 16 + g * 4;

  for (int qs = 0; qs < S_LEN / 16; ++qs) {
    const int qrow = qs * 16 + c;
    bf16x8 qbh_[2], qbl_[2];
#pragma unroll
    for (int h = 0; h < 2; ++h) {
      const float* src = Qb + (size_t)qrow * 64 + h * 32 + g * 8;
      float4 x = *(const float4*)(src);
      float4 y = *(const float4*)(src + 4);
      float xs[8] = {x.x, x.y, x.z, x.w, y.x, y.y, y.z, y.w};
#pragma unroll
      for (int e = 0; e < 8; ++e) {
        u16 hh, ll; bfsplit(xs[e] * SC, hh, ll);
        qbh_[h][e] = (short)hh; qbl_[h][e] = (short)ll;
      }
    }
    f32x4 acc = {0.f, 0.f, 0.f, 0.f};
#pragma unroll
    for (int h = 0; h < 2; ++h) {
      acc = MFMA32(kah[h], qbh_[h], acc);
      acc = MFMA32(kal[h], qbh_[h], acc);
      acc = MFMA32(kah[h], qbl_[h], acc);
    }
    u64 mw = mbits[(size_t)qrow * NCH + kc];
    unsigned nib = (unsigned)(mw >> shift) & 0xFu;
#pragma unroll
    for (int r = 0; r < 4; ++r) {
      float s = ((nib >> r) & 1) ? MASKED_L2 : acc[r];
      lp[r] += exp2f(s);
    }
  }
#pragma unroll
  for (int off = 1; off < 16; off <<= 1)
#pragma unroll
    for (int r = 0; r < 4; ++r) lp[r] += __shfl_xor(lp[r], off, 64);
  if (c == 0) {
    float4 o = {1.f / lp[0], 1.f / lp[1], 1.f / lp[2], 1.f / lp[3]};
    *(float4*)(il_out + (size_t)bh * S_LEN + kc * 64 + w * 16 + g * 4) = o;
  }
}

__global__ __launch_bounds__(256) void passC_out(
    const float* __restrict__ Q, const float* __restrict__ K,
    const float* __restrict__ V, const u64* __restrict__ mbits,
    const float* __restrict__ il_in, float* __restrict__ out) {
  __shared__ u16 kh_s[4096];
  __shared__ u16 kl_s[4096];
  __shared__ u16 vt_s[4096];
  __shared__ u16 p_s[4096];

  const int tid = threadIdx.x;
  const int lane = tid & 63;
  const int w = tid >> 6;
  const int c = lane & 15;
  const int g = lane >> 4;
  const int qc = blockIdx.x;
  const int bh = blockIdx.y;

  const float* Qb = Q + (size_t)bh * S_LEN * 64;
  const float* Kb = K + (size_t)bh * S_LEN * 64;
  const float* Vb = V + (size_t)bh * S_LEN * 64;

  bf16x8 qbh_[2], qbl_[2];
  {
    const int qrow = qc * 64 + w * 16 + c;
#pragma unroll
    for (int h = 0; h < 2; ++h) {
      const float* src = Qb + (size_t)qrow * 64 + h * 32 + g * 8;
      float4 x = *(const float4*)(src);
      float4 y = *(const float4*)(src + 4);
      float xs[8] = {x.x, x.y, x.z, x.w, y.x, y.y, y.z, y.w};
#pragma unroll
      for (int e = 0; e < 8; ++e) {
        u16 hh, ll; bfsplit(xs[e] * SC, hh, ll);
        qbh_[h][e] = (short)hh; qbl_[h][e] = (short)ll;
      }
    }
  }

  f32x4 oacc[4];
#pragma unroll
  for (int dt = 0; dt < 4; ++dt) oacc[dt] = (f32x4){0.f, 0.f, 0.f, 0.f};

  const int slot = tid & 15, r0 = tid >> 4;
  const int kv = tid & 63, dblk = tid >> 6;
  const int swc = (c & 7) << 3;
  const int pbase = w * 1024 + c * 64;

  for (int kc = 0; kc < NCH; ++kc) {
    __syncthreads();
#pragma unroll
    for (int p = 0; p < 4; ++p) {
      const int row = p * 16 + r0;
      float4 kx = *(const float4*)(Kb + (size_t)(kc * 64 + row) * 64 + slot * 4);
      float xs[4] = {kx.x, kx.y, kx.z, kx.w};
      u16 ha[4], la[4];
#pragma unroll
      for (int e = 0; e < 4; ++e) bfsplit(xs[e], ha[e], la[e]);
      const int idx = row * 64 + ((slot * 4) ^ ((row & 7) << 3));
      *(ushort4*)(kh_s + idx) = make_ushort4(ha[0], ha[1], ha[2], ha[3]);
      *(ushort4*)(kl_s + idx) = make_ushort4(la[0], la[1], la[2], la[3]);
    }
    {
      const float ilk = il_in[(size_t)bh * S_LEN + kc * 64 + kv];
#pragma unroll
      for (int u = 0; u < 4; ++u) {
        float4 vv = *(const float4*)(Vb + (size_t)(kc * 64 + kv) * 64 + dblk * 16 + u * 4);
        float xs[4] = {vv.x, vv.y, vv.z, vv.w};
#pragma unroll
        for (int e = 0; e < 4; ++e) {
          const int d = dblk * 16 + u * 4 + e;
          vt_s[d * 64 + (kv ^ ((d & 7) << 3))] = f2bf_rne(xs[e] * ilk);
        }
      }
    }
    __syncthreads();

    const u64 mw = mbits[(size_t)(qc * 64 + w * 16 + c) * NCH + kc];

#pragma unroll
    for (int kt = 0; kt < 4; ++kt) {
      const int kbase = (16 * kt + c) * 64;
      bf16x8 akh[2], akl[2];
#pragma unroll
      for (int h = 0; h < 2; ++h) {
        const int off = (h * 32 + g * 8) ^ swc;
        akh[h] = *(const bf16x8*)(kh_s + kbase + off);
        akl[h] = *(const bf16x8*)(kl_s + kbase + off);
      }
      f32x4 acc = {0.f, 0.f, 0.f, 0.f};
#pragma unroll
      for (int h = 0; h < 2; ++h) {
        acc = MFMA32(akh[h], qbh_[h], acc);
        acc = MFMA32(akl[h], qbh_[h], acc);
        acc = MFMA32(akh[h], qbl_[h], acc);
      }
      const unsigned nib = (unsigned)(mw >> (kt * 16 + g * 4)) & 0xFu;
      u16 pb[4];
#pragma unroll
      for (int r = 0; r < 4; ++r) {
        const float s = ((nib >> r) & 1) ? MASKED_L2 : acc[r];
        pb[r] = f2bf_rne(exp2f(s));
      }
      *(ushort4*)(p_s + pbase + ((kt * 16 + g * 4) ^ swc)) =
          make_ushort4(pb[0], pb[1], pb[2], pb[3]);
    }
    __syncthreads();

#pragma unroll
    for (int s = 0; s < 2; ++s) {
      const int koff = (s * 32 + 8 * g) ^ swc;
      bf16x8 pb8 = *(const bf16x8*)(p_s + pbase + koff);
#pragma unroll
      for (int dt = 0; dt < 4; ++dt) {
        bf16x8 av = *(const bf16x8*)(vt_s + (16 * dt + c) * 64 + koff);
        oacc[dt] = MFMA32(av, pb8, oacc[dt]);
      }
    }
  }

  float* ob = out + ((size_t)bh * S_LEN + qc * 64 + w * 16 + c) * 64;
#pragma unroll
  for (int dt = 0; dt < 4; ++dt) {
    float4 o = {oacc[dt][0], oacc[dt][1], oacc[dt][2], oacc[dt][3]};
    *(float4*)(ob + dt * 16 + g * 4) = o;
  }
}

extern "C" void kernel_launch(void* const* d_in, const int* in_sizes, int n_in,
                              void* d_out, int out_size, void* d_ws, size_t ws_size,
                              hipStream_t stream) {
  (void)in_sizes; (void)n_in; (void)out_size;
  const float* q = (const float*)d_in[0];
  const float* k = (const float*)d_in[1];
  const float* v = (const float*)d_in[2];
  const int* mask = (const int*)d_in[3];
  float* out = (float*)d_out;

  // ws: mbits(512KB) | part[4][32][2048] f32 (1MB) | qh|ql (linear planes)
  //     | kh_t|kl_t|w_t (swizzled tile planes), 8.4MB each
  u64* mbits = (u64*)d_ws;
  float* part = (float*)((char*)d_ws + 524288);
  const size_t PL = (size_t)N_BH * S_LEN * 64;       // 4,194,304 elems/plane
  u16* qh = (u16*)((char*)d_ws + 524288 + 1048576);
  u16* ql = qh + PL;
  u16* kh_t = ql + PL;
  u16* kl_t = kh_t + PL;
  u16* w_t = kl_t + PL;
  const size_t need = 524288 + 1048576 + 5 * PL * sizeof(u16); // 43,515,904

  pack_mask<<<dim3(S_LEN * NCH / 4), 256, 0, stream>>>(mask, mbits);

  if (ws_size >= need) {
    prep_q<<<dim3((int)(PL / 1024)), 256, 0, stream>>>(q, qh, ql);
    prep_k<<<dim3(NCH, N_BH), 256, 0, stream>>>(k, kh_t, kl_t);
    passA<<<dim3(8, N_BH, 4), 512, 0, stream>>>(qh, ql, kh_t, kl_t, mbits, part);
    prep_w<<<dim3(NCH, N_BH), 256, 0, stream>>>(v, part, w_t);
    passC<<<dim3(NCH, N_BH), 256, 0, stream>>>(qh, ql, kh_t, kl_t, w_t, mbits, out);
  } else {
    float* il = part;            // 256KB, fits
    dim3 grid(NCH, N_BH);
    passA_colsum<<<grid, 256, 0, stream>>>(q, k, mbits, il);
    passC_out<<<grid, 256, 0, stream>>>(q, k, v, mbits, il, out);
  }
}

// Round 7
// 260.906 us; speedup vs baseline: 2.0611x; 1.0010x over previous
//
#include <hip/hip_runtime.h>
#include <math.h>

// B=2, H=16, S=2048, DK=64
#define S_LEN 2048
#define NCH   32          // S/64 chunks
#define N_BH  32

typedef short bf16x8 __attribute__((ext_vector_type(8)));
typedef float f32x4  __attribute__((ext_vector_type(4)));
typedef unsigned short u16;
typedef unsigned short u16x8 __attribute__((ext_vector_type(8)));
typedef unsigned long long u64;

#define MFMA32(a,b,c) __builtin_amdgcn_mfma_f32_16x16x32_bf16((a),(b),(c),0,0,0)
#define EXP2(x) __builtin_amdgcn_exp2f(x)

// (1/sqrt(64)) * log2(e): scores in log2 units; exp2 = one v_exp_f32.
#define SC        0.18033688011112042f
// masked score in log2 units: exp2(-30)=9.3e-10 (negligible vs unmasked;
// a fully-masked column degrades to EXACT uniform 1/2048).
#define MASKED_L2 (-30.0f)

__device__ __forceinline__ u16 f2bf_rne(float x) {
  unsigned u = __float_as_uint(x);
  return (u16)((u + 0x7FFF + ((u >> 16) & 1)) >> 16);
}
// hi = bit-truncation, lo = RNE of residual; combined repr error ~2^-17
__device__ __forceinline__ void bfsplit(float x, u16& h, u16& l) {
  unsigned u = __float_as_uint(x);
  h = (u16)(u >> 16);
  float hf = __uint_as_float(u & 0xFFFF0000u);
  l = f2bf_rne(x - hf);
}

// ---------------------------------------------------------------------------
// pack_mask: word (row, wc) = ballot over k = wc*64 + lane.
// ---------------------------------------------------------------------------
__global__ __launch_bounds__(256) void pack_mask(
    const int* __restrict__ mask, u64* __restrict__ bits) {
  const int word = blockIdx.x * 4 + (threadIdx.x >> 6);
  const int lane = threadIdx.x & 63;
  const int row = word >> 5, wc = word & 31;
  int m = mask[(size_t)row * S_LEN + wc * 64 + lane];
  u64 b = __ballot(m != 0);
  if (lane == 0) bits[word] = b;
}

// ---------------------------------------------------------------------------
// prep_q: Q*SC -> (hi, lo) bf16 planes, linear [bh][row][64]. Coalesced.
// ---------------------------------------------------------------------------
__global__ __launch_bounds__(256) void prep_q(
    const float* __restrict__ src, u16* __restrict__ dh, u16* __restrict__ dl) {
  const size_t i = ((size_t)blockIdx.x * 256 + threadIdx.x) * 4;
  float4 x = *(const float4*)(src + i);
  float xs[4] = {x.x, x.y, x.z, x.w};
  u16 h[4], l[4];
#pragma unroll
  for (int e = 0; e < 4; ++e) bfsplit(xs[e] * SC, h[e], l[e]);
  *(ushort4*)(dh + i) = make_ushort4(h[0], h[1], h[2], h[3]);
  *(ushort4*)(dl + i) = make_ushort4(l[0], l[1], l[2], l[3]);
}

// ---------------------------------------------------------------------------
// prep_k: K -> (hi, lo) bf16, stored as SWIZZLED 64x64 tiles
// [bh][kc][ row*64 + (col ^ ((row&7)*8)) ]  -- the exact LDS layout passC
// wants, so passC staging is a pure 16B copy.
// ---------------------------------------------------------------------------
__global__ __launch_bounds__(256) void prep_k(
    const float* __restrict__ K, u16* __restrict__ kh_t, u16* __restrict__ kl_t) {
  __shared__ __align__(16) u16 th[4096];
  __shared__ __align__(16) u16 tl[4096];
  const int tid = threadIdx.x;
  const int kc = blockIdx.x, bh = blockIdx.y;
  const int slot = tid & 15, r0 = tid >> 4;
#pragma unroll
  for (int p = 0; p < 4; ++p) {
    const int row = p * 16 + r0;
    float4 kx = *(const float4*)(K + ((size_t)bh * S_LEN + kc * 64 + row) * 64 + slot * 4);
    float xs[4] = {kx.x, kx.y, kx.z, kx.w};
    u16 ha[4], la[4];
#pragma unroll
    for (int e = 0; e < 4; ++e) bfsplit(xs[e], ha[e], la[e]);
    const int idx = row * 64 + ((slot * 4) ^ ((row & 7) << 3));
    *(ushort4*)(th + idx) = make_ushort4(ha[0], ha[1], ha[2], ha[3]);
    *(ushort4*)(tl + idx) = make_ushort4(la[0], la[1], la[2], la[3]);
  }
  __syncthreads();
  u16* dh = kh_t + ((size_t)bh * NCH + kc) * 4096;
  u16* dl = kl_t + ((size_t)bh * NCH + kc) * 4096;
#pragma unroll
  for (int j = 0; j < 2; ++j) {
    *(u16x8*)(dh + j * 2048 + tid * 8) = *(const u16x8*)(th + j * 2048 + tid * 8);
    *(u16x8*)(dl + j * 2048 + tid * 8) = *(const u16x8*)(tl + j * 2048 + tid * 8);
  }
}

// ---------------------------------------------------------------------------
// prep_w: il[k] = 1/sum(partials); wT[d][k] = bf16(il*V[k][d]) as SWIZZLED
// 64x64 tiles [bh][kc][ d*64 + (k ^ ((d&7)*8)) ].
// ---------------------------------------------------------------------------
__global__ __launch_bounds__(256) void prep_w(
    const float* __restrict__ V, const float* __restrict__ part,
    u16* __restrict__ w_t) {
  __shared__ __align__(16) u16 ts[4096];
  const int tid = threadIdx.x;
  const int kc = blockIdx.x, bh = blockIdx.y;
  const int k = tid >> 2, dblk = (tid & 3) * 16;
  const size_t ko = (size_t)bh * S_LEN + kc * 64 + k;
  const float lsum = part[ko] + part[65536 + ko] + part[131072 + ko] + part[196608 + ko];
  const float ilk = 1.0f / lsum;
  const float* vb = V + ko * 64 + dblk;
#pragma unroll
  for (int u = 0; u < 4; ++u) {
    float4 x = *(const float4*)(vb + u * 4);
    float xs[4] = {x.x, x.y, x.z, x.w};
#pragma unroll
    for (int e = 0; e < 4; ++e) {
      const int d = dblk + u * 4 + e;
      ts[d * 64 + (k ^ ((d & 7) << 3))] = f2bf_rne(xs[e] * ilk);
    }
  }
  __syncthreads();
  u16* dst = w_t + ((size_t)bh * NCH + kc) * 4096;
#pragma unroll
  for (int j = 0; j < 2; ++j)
    *(u16x8*)(dst + j * 2048 + tid * 8) = *(const u16x8*)(ts + j * 2048 + tid * 8);
}

// ---------------------------------------------------------------------------
// passA: partial column sums over one q-quarter.
// Grid (8 kc-blocks, 32 bh, 4 qpart) x 512 thr. Wave owns 32 k (frags
// RESIDENT in regs -- launch_bounds(512,4) gives the 128-VGPR budget);
// q frags + mask double-buffered (prefetch next 16 rows before compute).
// ZERO LDS/barriers.
// ---------------------------------------------------------------------------
__global__ __launch_bounds__(512, 4) void passA(
    const u16* __restrict__ qh, const u16* __restrict__ ql,
    const u16* __restrict__ kh_t, const u16* __restrict__ kl_t,
    const u64* __restrict__ mbits, float* __restrict__ part) {
  const int tid = threadIdx.x;
  const int lane = tid & 63;
  const int w = tid >> 6;          // 0..7
  const int c = lane & 15;
  const int g = lane >> 4;
  const int bx = blockIdx.x;       // 0..7 (256 k each)
  const int bh = blockIdx.y;
  const int qp = blockIdx.z;       // 0..3 (512 q each)

  const u16* qhb = qh + (size_t)bh * S_LEN * 64;
  const u16* qlb = ql + (size_t)bh * S_LEN * 64;
  const size_t tbase = (size_t)bh * NCH * 4096;

  // K A-frags from swizzled tiles (resident for the whole kernel)
  bf16x8 kah[2][2], kal[2][2];
#pragma unroll
  for (int t = 0; t < 2; ++t) {
    const int rg = w * 32 + t * 16;                // 0..240
    const size_t tb = tbase + (size_t)(bx * 4 + (rg >> 6)) * 4096;
    const int row = (rg & 63) + c;
#pragma unroll
    for (int h = 0; h < 2; ++h) {
      const int off = (h * 32 + g * 8) ^ ((c & 7) << 3);
      kah[t][h] = *(const bf16x8*)(kh_t + tb + row * 64 + off);
      kal[t][h] = *(const bf16x8*)(kl_t + tb + row * 64 + off);
    }
  }

  float lp[2][4] = {{0.f, 0.f, 0.f, 0.f}, {0.f, 0.f, 0.f, 0.f}};
  const int word = bx * 4 + (w >> 1);              // same for t=0,1
  const int sh0 = (w & 1) * 32 + g * 4;
  const int qbase = qp * 512 + c;

  // double-buffered q frags + mask
  bf16x8 h0[2], l0[2], h1[2], l1[2];
  u64 m0, m1;

  auto loadq = [&](int qrow, bf16x8* bhf, bf16x8* blf, u64& mw) {
#pragma unroll
    for (int h = 0; h < 2; ++h) {
      bhf[h] = *(const bf16x8*)(qhb + (size_t)qrow * 64 + h * 32 + g * 8);
      blf[h] = *(const bf16x8*)(qlb + (size_t)qrow * 64 + h * 32 + g * 8);
    }
    mw = mbits[(size_t)qrow * NCH + word];
  };
  auto compute = [&](const bf16x8* bhf, const bf16x8* blf, u64 mw) {
#pragma unroll
    for (int t = 0; t < 2; ++t) {
      f32x4 acc = {0.f, 0.f, 0.f, 0.f};
#pragma unroll
      for (int h = 0; h < 2; ++h) {     // IDENTICAL order in passC
        acc = MFMA32(kah[t][h], bhf[h], acc);
        acc = MFMA32(kal[t][h], bhf[h], acc);
        acc = MFMA32(kah[t][h], blf[h], acc);
      }
      const unsigned nib = (unsigned)(mw >> (sh0 + t * 16)) & 0xFu;
#pragma unroll
      for (int r = 0; r < 4; ++r) {
        const float s = ((nib >> r) & 1) ? MASKED_L2 : acc[r];
        lp[t][r] += EXP2(s);
      }
    }
  };

  loadq(qbase, h0, l0, m0);                        // prologue: qs=0
#pragma unroll 1
  for (int qs = 0; qs < 32; qs += 2) {
    loadq(qbase + (qs + 1) * 16, h1, l1, m1);      // prefetch odd
    compute(h0, l0, m0);                           // consume even
    loadq(((qp * 512 + (qs + 2) * 16) & (S_LEN - 1)) + c, h0, l0, m0);
    compute(h1, l1, m1);                           // consume odd
  }

  // reduce over the 16 c-lanes of each g-group
#pragma unroll
  for (int off = 1; off < 16; off <<= 1)
#pragma unroll
    for (int t = 0; t < 2; ++t)
#pragma unroll
      for (int r = 0; r < 4; ++r) lp[t][r] += __shfl_xor(lp[t][r], off, 64);
  if (c == 0) {
#pragma unroll
    for (int t = 0; t < 2; ++t) {
      float4 o = {lp[t][0], lp[t][1], lp[t][2], lp[t][3]};
      *(float4*)(part + (size_t)qp * 65536 + (size_t)bh * S_LEN
                 + bx * 256 + w * 32 + t * 16 + g * 4) = o;
    }
  }
}

// ---------------------------------------------------------------------------
// passC: out[q,d] = sum_k exp2(s~[q,k]) * wT[d,k].
// 4 waves share an LDS-staged chunk {kh|kl|wT} (24KB, pre-swizzled tiles ->
// staging is a pure 16B copy). T14 async-split: next chunk's global loads
// issue before compute, ds_write after the barrier. launch_bounds(256,4)
// gives the 128-VGPR budget so stg[6]+frags+oacc stay resident.
// ---------------------------------------------------------------------------
__global__ __launch_bounds__(256, 4) void passC(
    const u16* __restrict__ qh, const u16* __restrict__ ql,
    const u16* __restrict__ kh_t, const u16* __restrict__ kl_t,
    const u16* __restrict__ w_t, const u64* __restrict__ mbits,
    float* __restrict__ out) {
  __shared__ __align__(16) u16 sbuf[12288];   // [kh:4096 | kl:4096 | wT:4096]
  __shared__ __align__(16) u16 p_s[4096];     // per-wave [16 q][64 k], swizzled

  const int tid = threadIdx.x;
  const int lane = tid & 63;
  const int w = tid >> 6;
  const int c = lane & 15;
  const int g = lane >> 4;
  const int qc = blockIdx.x;
  const int bh = blockIdx.y;

  const u16* qhb = qh + (size_t)bh * S_LEN * 64;
  const u16* qlb = ql + (size_t)bh * S_LEN * 64;
  const u16* tb_h = kh_t + (size_t)bh * NCH * 4096;
  const u16* tb_l = kl_t + (size_t)bh * NCH * 4096;
  const u16* tb_w = w_t + (size_t)bh * NCH * 4096;

  const int qrow = qc * 64 + w * 16 + c;
  bf16x8 qbh_[2], qbl_[2];
#pragma unroll
  for (int h = 0; h < 2; ++h) {
    qbh_[h] = *(const bf16x8*)(qhb + (size_t)qrow * 64 + h * 32 + g * 8);
    qbl_[h] = *(const bf16x8*)(qlb + (size_t)qrow * 64 + h * 32 + g * 8);
  }

  f32x4 oacc[4];
#pragma unroll
  for (int dt = 0; dt < 4; ++dt) oacc[dt] = (f32x4){0.f, 0.f, 0.f, 0.f};

  const int swc = (c & 7) << 3;
  const int pbase = w * 1024 + c * 64;
  const int so = tid * 8;                     // staging offset (u16 units)

  // prologue: load chunk 0 into staging regs
  u16x8 stg[6];
#pragma unroll
  for (int j = 0; j < 2; ++j) {
    stg[0 + j] = *(const u16x8*)(tb_h + j * 2048 + so);
    stg[2 + j] = *(const u16x8*)(tb_l + j * 2048 + so);
    stg[4 + j] = *(const u16x8*)(tb_w + j * 2048 + so);
  }

  for (int kc = 0; kc < NCH; ++kc) {
    __syncthreads();                          // prior readers of sbuf done
    // commit staged regs (compiler inserts vmcnt wait here)
#pragma unroll
    for (int j = 0; j < 2; ++j) {
      *(u16x8*)(sbuf + j * 2048 + so) = stg[0 + j];
      *(u16x8*)(sbuf + 4096 + j * 2048 + so) = stg[2 + j];
      *(u16x8*)(sbuf + 8192 + j * 2048 + so) = stg[4 + j];
    }
    __syncthreads();                          // sbuf ready
    // issue next chunk's loads NOW; consumed after next barrier (T14)
    if (kc + 1 < NCH) {
      const size_t nb = (size_t)(kc + 1) * 4096;
#pragma unroll
      for (int j = 0; j < 2; ++j) {
        stg[0 + j] = *(const u16x8*)(tb_h + nb + j * 2048 + so);
        stg[2 + j] = *(const u16x8*)(tb_l + nb + j * 2048 + so);
        stg[4 + j] = *(const u16x8*)(tb_w + nb + j * 2048 + so);
      }
    }

    const u64 mw = mbits[(size_t)qrow * NCH + kc];

    // QK^T + mask + exp2 -> P (per-wave LDS tile)
#pragma unroll
    for (int kt = 0; kt < 4; ++kt) {
      const int kbase = (16 * kt + c) * 64;
      bf16x8 akh[2], akl[2];
#pragma unroll
      for (int h = 0; h < 2; ++h) {
        const int off = (h * 32 + g * 8) ^ swc;
        akh[h] = *(const bf16x8*)(sbuf + kbase + off);
        akl[h] = *(const bf16x8*)(sbuf + 4096 + kbase + off);
      }
      f32x4 acc = {0.f, 0.f, 0.f, 0.f};
#pragma unroll
      for (int h = 0; h < 2; ++h) {     // IDENTICAL order to passA
        acc = MFMA32(akh[h], qbh_[h], acc);
        acc = MFMA32(akl[h], qbh_[h], acc);
        acc = MFMA32(akh[h], qbl_[h], acc);
      }
      const unsigned nib = (unsigned)(mw >> (kt * 16 + g * 4)) & 0xFu;
      u16 pb[4];
#pragma unroll
      for (int r = 0; r < 4; ++r) {
        const float s = ((nib >> r) & 1) ? MASKED_L2 : acc[r];
        pb[r] = f2bf_rne(EXP2(s));
      }
      *(ushort4*)(p_s + pbase + ((kt * 16 + g * 4) ^ swc)) =
          make_ushort4(pb[0], pb[1], pb[2], pb[3]);
    }

    // PV: oacc[dt] += wT[16dt.., k-slice] * P[k-slice, q]  (2 slices of 32)
#pragma unroll
    for (int s2 = 0; s2 < 2; ++s2) {
      const int koff = (s2 * 32 + g * 8) ^ swc;
      bf16x8 pb8 = *(const bf16x8*)(p_s + pbase + koff);
#pragma unroll
      for (int dt = 0; dt < 4; ++dt) {
        bf16x8 av = *(const bf16x8*)(sbuf + 8192 + (16 * dt + c) * 64 + koff);
        oacc[dt] = MFMA32(av, pb8, oacc[dt]);
      }
    }
  }

  // epilogue: lane (c,g) owns row q = qrow, cols d = 16dt+4g+r
  float* ob = out + ((size_t)bh * S_LEN + qrow) * 64;
#pragma unroll
  for (int dt = 0; dt < 4; ++dt) {
    float4 o = {oacc[dt][0], oacc[dt][1], oacc[dt][2], oacc[dt][3]};
    *(float4*)(ob + dt * 16 + g * 4) = o;
  }
}

// ===========================================================================
// FALLBACK (round-4 proven kernels) — used when ws_size is too small.
// ===========================================================================
__global__ __launch_bounds__(256) void passA_colsum(
    const float* __restrict__ Q, const float* __restrict__ K,
    const u64* __restrict__ mbits, float* __restrict__ il_out) {
  const int tid = threadIdx.x;
  const int lane = tid & 63;
  const int w = tid >> 6;
  const int c = lane & 15;
  const int g = lane >> 4;
  const int kc = blockIdx.x;
  const int bh = blockIdx.y;

  const float* Qb = Q + (size_t)bh * S_LEN * 64;
  const float* Kb = K + (size_t)bh * S_LEN * 64;

  bf16x8 kah[2], kal[2];
  {
    const int krow = kc * 64 + w * 16 + c;
#pragma unroll
    for (int h = 0; h < 2; ++h) {
      const float* src = Kb + (size_t)krow * 64 + h * 32 + g * 8;
      float4 x = *(const float4*)(src);
      float4 y = *(const float4*)(src + 4);
      float xs[8] = {x.x, x.y, x.z, x.w, y.x, y.y, y.z, y.w};
#pragma unroll
      for (int e = 0; e < 8; ++e) {
        u16 hh, ll; bfsplit(xs[e], hh, ll);
        kah[h][e] = (short)hh; kal[h][e] = (short)ll;
      }
    }
  }

  float lp[4] = {0.f, 0.f, 0.f, 0.f};
  const int shift = w * 16 + g * 4;

  for (int qs = 0; qs < S_LEN / 16; ++qs) {
    const int qrow = qs * 16 + c;
    bf16x8 qbh_[2], qbl_[2];
#pragma unroll
    for (int h = 0; h < 2; ++h) {
      const float* src = Qb + (size_t)qrow * 64 + h * 32 + g * 8;
      float4 x = *(const float4*)(src);
      float4 y = *(const float4*)(src + 4);
      float xs[8] = {x.x, x.y, x.z, x.w, y.x, y.y, y.z, y.w};
#pragma unroll
      for (int e = 0; e < 8; ++e) {
        u16 hh, ll; bfsplit(xs[e] * SC, hh, ll);
        qbh_[h][e] = (short)hh; qbl_[h][e] = (short)ll;
      }
    }
    f32x4 acc = {0.f, 0.f, 0.f, 0.f};
#pragma unroll
    for (int h = 0; h < 2; ++h) {
      acc = MFMA32(kah[h], qbh_[h], acc);
      acc = MFMA32(kal[h], qbh_[h], acc);
      acc = MFMA32(kah[h], qbl_[h], acc);
    }
    u64 mw = mbits[(size_t)qrow * NCH + kc];
    unsigned nib = (unsigned)(mw >> shift) & 0xFu;
#pragma unroll
    for (int r = 0; r < 4; ++r) {
      float s = ((nib >> r) & 1) ? MASKED_L2 : acc[r];
      lp[r] += exp2f(s);
    }
  }
#pragma unroll
  for (int off = 1; off < 16; off <<= 1)
#pragma unroll
    for (int r = 0; r < 4; ++r) lp[r] += __shfl_xor(lp[r], off, 64);
  if (c == 0) {
    float4 o = {1.f / lp[0], 1.f / lp[1], 1.f / lp[2], 1.f / lp[3]};
    *(float4*)(il_out + (size_t)bh * S_LEN + kc * 64 + w * 16 + g * 4) = o;
  }
}

__global__ __launch_bounds__(256) void passC_out(
    const float* __restrict__ Q, const float* __restrict__ K,
    const float* __restrict__ V, const u64* __restrict__ mbits,
    const float* __restrict__ il_in, float* __restrict__ out) {
  __shared__ u16 kh_s[4096];
  __shared__ u16 kl_s[4096];
  __shared__ u16 vt_s[4096];
  __shared__ u16 p_s[4096];

  const int tid = threadIdx.x;
  const int lane = tid & 63;
  const int w = tid >> 6;
  const int c = lane & 15;
  const int g = lane >> 4;
  const int qc = blockIdx.x;
  const int bh = blockIdx.y;

  const float* Qb = Q + (size_t)bh * S_LEN * 64;
  const float* Kb = K + (size_t)bh * S_LEN * 64;
  const float* Vb = V + (size_t)bh * S_LEN * 64;

  bf16x8 qbh_[2], qbl_[2];
  {
    const int qrow = qc * 64 + w * 16 + c;
#pragma unroll
    for (int h = 0; h < 2; ++h) {
      const float* src = Qb + (size_t)qrow * 64 + h * 32 + g * 8;
      float4 x = *(const float4*)(src);
      float4 y = *(const float4*)(src + 4);
      float xs[8] = {x.x, x.y, x.z, x.w, y.x, y.y, y.z, y.w};
#pragma unroll
      for (int e = 0; e < 8; ++e) {
        u16 hh, ll; bfsplit(xs[e] * SC, hh, ll);
        qbh_[h][e] = (short)hh; qbl_[h][e] = (short)ll;
      }
    }
  }

  f32x4 oacc[4];
#pragma unroll
  for (int dt = 0; dt < 4; ++dt) oacc[dt] = (f32x4){0.f, 0.f, 0.f, 0.f};

  const int slot = tid & 15, r0 = tid >> 4;
  const int kv = tid & 63, dblk = tid >> 6;
  const int swc = (c & 7) << 3;
  const int pbase = w * 1024 + c * 64;

  for (int kc = 0; kc < NCH; ++kc) {
    __syncthreads();
#pragma unroll
    for (int p = 0; p < 4; ++p) {
      const int row = p * 16 + r0;
      float4 kx = *(const float4*)(Kb + (size_t)(kc * 64 + row) * 64 + slot * 4);
      float xs[4] = {kx.x, kx.y, kx.z, kx.w};
      u16 ha[4], la[4];
#pragma unroll
      for (int e = 0; e < 4; ++e) bfsplit(xs[e], ha[e], la[e]);
      const int idx = row * 64 + ((slot * 4) ^ ((row & 7) << 3));
      *(ushort4*)(kh_s + idx) = make_ushort4(ha[0], ha[1], ha[2], ha[3]);
      *(ushort4*)(kl_s + idx) = make_ushort4(la[0], la[1], la[2], la[3]);
    }
    {
      const float ilk = il_in[(size_t)bh * S_LEN + kc * 64 + kv];
#pragma unroll
      for (int u = 0; u < 4; ++u) {
        float4 vv = *(const float4*)(Vb + (size_t)(kc * 64 + kv) * 64 + dblk * 16 + u * 4);
        float xs[4] = {vv.x, vv.y, vv.z, vv.w};
#pragma unroll
        for (int e = 0; e < 4; ++e) {
          const int d = dblk * 16 + u * 4 + e;
          vt_s[d * 64 + (kv ^ ((d & 7) << 3))] = f2bf_rne(xs[e] * ilk);
        }
      }
    }
    __syncthreads();

    const u64 mw = mbits[(size_t)(qc * 64 + w * 16 + c) * NCH + kc];

#pragma unroll
    for (int kt = 0; kt < 4; ++kt) {
      const int kbase = (16 * kt + c) * 64;
      bf16x8 akh[2], akl[2];
#pragma unroll
      for (int h = 0; h < 2; ++h) {
        const int off = (h * 32 + g * 8) ^ swc;
        akh[h] = *(const bf16x8*)(kh_s + kbase + off);
        akl[h] = *(const bf16x8*)(kl_s + kbase + off);
      }
      f32x4 acc = {0.f, 0.f, 0.f, 0.f};
#pragma unroll
      for (int h = 0; h < 2; ++h) {
        acc = MFMA32(akh[h], qbh_[h], acc);
        acc = MFMA32(akl[h], qbh_[h], acc);
        acc = MFMA32(akh[h], qbl_[h], acc);
      }
      const unsigned nib = (unsigned)(mw >> (kt * 16 + g * 4)) & 0xFu;
      u16 pb[4];
#pragma unroll
      for (int r = 0; r < 4; ++r) {
        const float s = ((nib >> r) & 1) ? MASKED_L2 : acc[r];
        pb[r] = f2bf_rne(exp2f(s));
      }
      *(ushort4*)(p_s + pbase + ((kt * 16 + g * 4) ^ swc)) =
          make_ushort4(pb[0], pb[1], pb[2], pb[3]);
    }
    __syncthreads();

#pragma unroll
    for (int s = 0; s < 2; ++s) {
      const int koff = (s * 32 + 8 * g) ^ swc;
      bf16x8 pb8 = *(const bf16x8*)(p_s + pbase + koff);
#pragma unroll
      for (int dt = 0; dt < 4; ++dt) {
        bf16x8 av = *(const bf16x8*)(vt_s + (16 * dt + c) * 64 + koff);
        oacc[dt] = MFMA32(av, pb8, oacc[dt]);
      }
    }
  }

  float* ob = out + ((size_t)bh * S_LEN + qc * 64 + w * 16 + c) * 64;
#pragma unroll
  for (int dt = 0; dt < 4; ++dt) {
    float4 o = {oacc[dt][0], oacc[dt][1], oacc[dt][2], oacc[dt][3]};
    *(float4*)(ob + dt * 16 + g * 4) = o;
  }
}

extern "C" void kernel_launch(void* const* d_in, const int* in_sizes, int n_in,
                              void* d_out, int out_size, void* d_ws, size_t ws_size,
                              hipStream_t stream) {
  (void)in_sizes; (void)n_in; (void)out_size;
  const float* q = (const float*)d_in[0];
  const float* k = (const float*)d_in[1];
  const float* v = (const float*)d_in[2];
  const int* mask = (const int*)d_in[3];
  float* out = (float*)d_out;

  // ws: mbits(512KB) | part[4][32][2048] f32 (1MB) | qh|ql (linear planes)
  //     | kh_t|kl_t|w_t (swizzled tile planes), 8.4MB each
  u64* mbits = (u64*)d_ws;
  float* part = (float*)((char*)d_ws + 524288);
  const size_t PL = (size_t)N_BH * S_LEN * 64;       // 4,194,304 elems/plane
  u16* qh = (u16*)((char*)d_ws + 524288 + 1048576);
  u16* ql = qh + PL;
  u16* kh_t = ql + PL;
  u16* kl_t = kh_t + PL;
  u16* w_t = kl_t + PL;
  const size_t need = 524288 + 1048576 + 5 * PL * sizeof(u16); // 43,515,904

  pack_mask<<<dim3(S_LEN * NCH / 4), 256, 0, stream>>>(mask, mbits);

  if (ws_size >= need) {
    prep_q<<<dim3((int)(PL / 1024)), 256, 0, stream>>>(q, qh, ql);
    prep_k<<<dim3(NCH, N_BH), 256, 0, stream>>>(k, kh_t, kl_t);
    passA<<<dim3(8, N_BH, 4), 512, 0, stream>>>(qh, ql, kh_t, kl_t, mbits, part);
    prep_w<<<dim3(NCH, N_BH), 256, 0, stream>>>(v, part, w_t);
    passC<<<dim3(NCH, N_BH), 256, 0, stream>>>(qh, ql, kh_t, kl_t, w_t, mbits, out);
  } else {
    float* il = part;            // 256KB, fits
    dim3 grid(NCH, N_BH);
    passA_colsum<<<grid, 256, 0, stream>>>(q, k, mbits, il);
    passC_out<<<grid, 256, 0, stream>>>(q, k, v, mbits, il, out);
  }
}

// Round 8
// 179.092 us; speedup vs baseline: 3.0027x; 1.4568x over previous
//
#include <hip/hip_runtime.h>
#include <math.h>

// B=2, H=16, S=2048, DK=64
#define S_LEN 2048
#define NCH   32          // S/64 chunks
#define N_BH  32

typedef short bf16x8 __attribute__((ext_vector_type(8)));
typedef float f32x4  __attribute__((ext_vector_type(4)));
typedef unsigned short u16;
typedef unsigned short u16x8 __attribute__((ext_vector_type(8)));
typedef unsigned long long u64;

#define MFMA32(a,b,c) __builtin_amdgcn_mfma_f32_16x16x32_bf16((a),(b),(c),0,0,0)
#define EXP2(x) __builtin_amdgcn_exp2f(x)

// (1/sqrt(64)) * log2(e): scores in log2 units; exp2 = one v_exp_f32.
#define SC        0.18033688011112042f
// masked score in log2 units: exp2(-30)=9.3e-10 (negligible vs unmasked;
// a fully-masked column degrades to EXACT uniform 1/2048).
#define MASKED_L2 (-30.0f)

__device__ __forceinline__ u16 f2bf_rne(float x) {
  unsigned u = __float_as_uint(x);
  return (u16)((u + 0x7FFF + ((u >> 16) & 1)) >> 16);
}
// hi = bit-truncation, lo = RNE of residual; combined repr error ~2^-17
__device__ __forceinline__ void bfsplit(float x, u16& h, u16& l) {
  unsigned u = __float_as_uint(x);
  h = (u16)(u >> 16);
  float hf = __uint_as_float(u & 0xFFFF0000u);
  l = f2bf_rne(x - hf);
}

// ---------------------------------------------------------------------------
// pack_mask: word (row, wc) = ballot over k = wc*64 + lane.
// ---------------------------------------------------------------------------
__global__ __launch_bounds__(256) void pack_mask(
    const int* __restrict__ mask, u64* __restrict__ bits) {
  const int word = blockIdx.x * 4 + (threadIdx.x >> 6);
  const int lane = threadIdx.x & 63;
  const int row = word >> 5, wc = word & 31;
  int m = mask[(size_t)row * S_LEN + wc * 64 + lane];
  u64 b = __ballot(m != 0);
  if (lane == 0) bits[word] = b;
}

// ---------------------------------------------------------------------------
// prep_q: Q*SC -> (hi, lo) bf16 planes stored as SWIZZLED 16x64 tiles:
//   plane[tile*1024 + row16*64 + (col ^ ((row16&7)*8))]
// This is the exact layout passA's LDS staging copies and both passes read.
// ---------------------------------------------------------------------------
__global__ __launch_bounds__(256) void prep_q(
    const float* __restrict__ src, u16* __restrict__ dh, u16* __restrict__ dl) {
  const int tid = threadIdx.x;
  const int slot = tid & 15, r0 = tid >> 4;
  const size_t rowbase = (size_t)blockIdx.x * 64;   // 64 rows (4 tiles) / block
#pragma unroll
  for (int p = 0; p < 4; ++p) {
    const size_t row = rowbase + p * 16 + r0;
    float4 x = *(const float4*)(src + row * 64 + slot * 4);
    float xs[4] = {x.x, x.y, x.z, x.w};
    u16 h[4], l[4];
#pragma unroll
    for (int e = 0; e < 4; ++e) bfsplit(xs[e] * SC, h[e], l[e]);
    const size_t dst = (rowbase / 16 + p) * 1024 + (size_t)r0 * 64
                     + ((slot * 4) ^ ((r0 & 7) << 3));
    *(ushort4*)(dh + dst) = make_ushort4(h[0], h[1], h[2], h[3]);
    *(ushort4*)(dl + dst) = make_ushort4(l[0], l[1], l[2], l[3]);
  }
}

// ---------------------------------------------------------------------------
// prep_k: K -> (hi, lo) bf16, SWIZZLED 64x64 tiles
// [bh][kc][ row*64 + (col ^ ((row&7)*8)) ] -- pure-copy staging for passC.
// ---------------------------------------------------------------------------
__global__ __launch_bounds__(256) void prep_k(
    const float* __restrict__ K, u16* __restrict__ kh_t, u16* __restrict__ kl_t) {
  __shared__ __align__(16) u16 th[4096];
  __shared__ __align__(16) u16 tl[4096];
  const int tid = threadIdx.x;
  const int kc = blockIdx.x, bh = blockIdx.y;
  const int slot = tid & 15, r0 = tid >> 4;
#pragma unroll
  for (int p = 0; p < 4; ++p) {
    const int row = p * 16 + r0;
    float4 kx = *(const float4*)(K + ((size_t)bh * S_LEN + kc * 64 + row) * 64 + slot * 4);
    float xs[4] = {kx.x, kx.y, kx.z, kx.w};
    u16 ha[4], la[4];
#pragma unroll
    for (int e = 0; e < 4; ++e) bfsplit(xs[e], ha[e], la[e]);
    const int idx = row * 64 + ((slot * 4) ^ ((row & 7) << 3));
    *(ushort4*)(th + idx) = make_ushort4(ha[0], ha[1], ha[2], ha[3]);
    *(ushort4*)(tl + idx) = make_ushort4(la[0], la[1], la[2], la[3]);
  }
  __syncthreads();
  u16* dh = kh_t + ((size_t)bh * NCH + kc) * 4096;
  u16* dl = kl_t + ((size_t)bh * NCH + kc) * 4096;
#pragma unroll
  for (int j = 0; j < 2; ++j) {
    *(u16x8*)(dh + j * 2048 + tid * 8) = *(const u16x8*)(th + j * 2048 + tid * 8);
    *(u16x8*)(dl + j * 2048 + tid * 8) = *(const u16x8*)(tl + j * 2048 + tid * 8);
  }
}

// ---------------------------------------------------------------------------
// prep_w: il[k] = 1/sum(2 partials); wT[d][k] = bf16(il*V[k][d]) as SWIZZLED
// 64x64 tiles [bh][kc][ d*64 + (k ^ ((d&7)*8)) ].
// ---------------------------------------------------------------------------
__global__ __launch_bounds__(256) void prep_w(
    const float* __restrict__ V, const float* __restrict__ part,
    u16* __restrict__ w_t) {
  __shared__ __align__(16) u16 ts[4096];
  const int tid = threadIdx.x;
  const int kc = blockIdx.x, bh = blockIdx.y;
  const int k = tid >> 2, dblk = (tid & 3) * 16;
  const size_t ko = (size_t)bh * S_LEN + kc * 64 + k;
  const float lsum = part[ko] + part[65536 + ko];
  const float ilk = 1.0f / lsum;
  const float* vb = V + ko * 64 + dblk;
#pragma unroll
  for (int u = 0; u < 4; ++u) {
    float4 x = *(const float4*)(vb + u * 4);
    float xs[4] = {x.x, x.y, x.z, x.w};
#pragma unroll
    for (int e = 0; e < 4; ++e) {
      const int d = dblk + u * 4 + e;
      ts[d * 64 + (k ^ ((d & 7) << 3))] = f2bf_rne(xs[e] * ilk);
    }
  }
  __syncthreads();
  u16* dst = w_t + ((size_t)bh * NCH + kc) * 4096;
#pragma unroll
  for (int j = 0; j < 2; ++j)
    *(u16x8*)(dst + j * 2048 + tid * 8) = *(const u16x8*)(ts + j * 2048 + tid * 8);
}

// ---------------------------------------------------------------------------
// passA: partial column sums il_part[k] = sum_{q in half} exp2(s~[q,k]).
// Grid (8 bx, 32 bh, 2 qp) x 512. Wave owns 32 k (K-frags resident, 32 VGPR).
// The 32-row q step-tile is SHARED: staged in LDS (8KB) with the T14 split
// (issue next step's 16B/thread load right after barrier, ds_write-commit at
// the next barrier, compute meanwhile). 24 MFMA / step / wave.
// ---------------------------------------------------------------------------
__global__ __launch_bounds__(512, 4) void passA(
    const u16* __restrict__ qh, const u16* __restrict__ ql,
    const u16* __restrict__ kh_t, const u16* __restrict__ kl_t,
    const u64* __restrict__ mbits, float* __restrict__ part) {
  __shared__ __align__(16) u16 qbuf[4096];   // [qh 32x64 | ql 32x64] swizzled

  const int tid = threadIdx.x;
  const int lane = tid & 63;
  const int w = tid >> 6;          // 0..7
  const int c = lane & 15;
  const int g = lane >> 4;
  const int bx = blockIdx.x;       // 0..7 (256 k each)
  const int bh = blockIdx.y;
  const int qp = blockIdx.z;       // 0..1 (1024 q each)

  const size_t tbase = (size_t)bh * NCH * 4096;

  // resident K A-frags (2 x 16-k tiles), from swizzled tiles
  bf16x8 kah[2][2], kal[2][2];
#pragma unroll
  for (int t = 0; t < 2; ++t) {
    const int rg = w * 32 + t * 16;                // 0..240
    const size_t tb = tbase + (size_t)(bx * 4 + (rg >> 6)) * 4096;
    const int row = (rg & 63) + c;
#pragma unroll
    for (int h = 0; h < 2; ++h) {
      const int off = (h * 32 + g * 8) ^ ((c & 7) << 3);
      kah[t][h] = *(const bf16x8*)(kh_t + tb + row * 64 + off);
      kal[t][h] = *(const bf16x8*)(kl_t + tb + row * 64 + off);
    }
  }

  // staging role: thread stages 16B; waves 0-3 -> qh half, 4-7 -> ql half
  const u16* sbase = ((tid < 256) ? qh : ql) + (size_t)bh * S_LEN * 64;
  const int soff = (tid & 255) * 8;
  const int ldsoff = ((tid < 256) ? 0 : 2048) + soff;

  u16x8 stg = *(const u16x8*)(sbase + (size_t)(qp * 64) * 1024 + soff);

  float lp[2][4] = {{0.f, 0.f, 0.f, 0.f}, {0.f, 0.f, 0.f, 0.f}};
  const int word = bx * 4 + (w >> 1);
  const int sh0 = (w & 1) * 32;
  const int swc = (c & 7) << 3;

  for (int qs = 0; qs < 32; ++qs) {
    __syncthreads();                       // prior readers of qbuf done
    *(u16x8*)(qbuf + ldsoff) = stg;        // commit (waits vmcnt implicitly)
    __syncthreads();                       // qbuf ready
    if (qs + 1 < 32)                       // T14: issue next step's loads now
      stg = *(const u16x8*)(sbase + (size_t)(qp * 64 + (qs + 1) * 2) * 1024 + soff);

#pragma unroll
    for (int sub = 0; sub < 2; ++sub) {
      bf16x8 fh[2], fl[2];
      const int rb = sub * 1024 + c * 64;
#pragma unroll
      for (int h = 0; h < 2; ++h) {
        const int off = (h * 32 + g * 8) ^ swc;
        fh[h] = *(const bf16x8*)(qbuf + rb + off);
        fl[h] = *(const bf16x8*)(qbuf + 2048 + rb + off);
      }
      const int qrow = qp * 1024 + qs * 32 + sub * 16 + c;
      const u64 mw = mbits[(size_t)qrow * NCH + word];
#pragma unroll
      for (int t = 0; t < 2; ++t) {
        f32x4 acc = {0.f, 0.f, 0.f, 0.f};
#pragma unroll
        for (int h = 0; h < 2; ++h) {      // IDENTICAL order in passC
          acc = MFMA32(kah[t][h], fh[h], acc);
          acc = MFMA32(kal[t][h], fh[h], acc);
          acc = MFMA32(kah[t][h], fl[h], acc);
        }
        const unsigned nib = (unsigned)(mw >> (sh0 + t * 16 + g * 4)) & 0xFu;
#pragma unroll
        for (int r = 0; r < 4; ++r) {
          const float s = ((nib >> r) & 1) ? MASKED_L2 : acc[r];
          lp[t][r] += EXP2(s);
        }
      }
    }
  }

  // reduce over the 16 c-lanes of each g-group
#pragma unroll
  for (int off = 1; off < 16; off <<= 1)
#pragma unroll
    for (int t = 0; t < 2; ++t)
#pragma unroll
      for (int r = 0; r < 4; ++r) lp[t][r] += __shfl_xor(lp[t][r], off, 64);
  if (c == 0) {
#pragma unroll
    for (int t = 0; t < 2; ++t) {
      float4 o = {lp[t][0], lp[t][1], lp[t][2], lp[t][3]};
      *(float4*)(part + (size_t)qp * 65536 + (size_t)bh * S_LEN
                 + bx * 256 + w * 32 + t * 16 + g * 4) = o;
    }
  }
}

// ---------------------------------------------------------------------------
// passC: out[q,d] = sum_k exp2(s~[q,k]) * wT[d,k].
// 4 waves share an LDS-staged chunk {kh|kl|wT} (24KB, pre-swizzled tiles ->
// pure 16B copy staging). T14 async-split prefetch. Per-wave P tile in LDS.
// ---------------------------------------------------------------------------
__global__ __launch_bounds__(256, 4) void passC(
    const u16* __restrict__ qh, const u16* __restrict__ ql,
    const u16* __restrict__ kh_t, const u16* __restrict__ kl_t,
    const u16* __restrict__ w_t, const u64* __restrict__ mbits,
    float* __restrict__ out) {
  __shared__ __align__(16) u16 sbuf[12288];   // [kh:4096 | kl:4096 | wT:4096]
  __shared__ __align__(16) u16 p_s[4096];     // per-wave [16 q][64 k], swizzled

  const int tid = threadIdx.x;
  const int lane = tid & 63;
  const int w = tid >> 6;
  const int c = lane & 15;
  const int g = lane >> 4;
  const int qc = blockIdx.x;
  const int bh = blockIdx.y;

  const u16* qhb = qh + (size_t)bh * S_LEN * 64;
  const u16* qlb = ql + (size_t)bh * S_LEN * 64;
  const u16* tb_h = kh_t + (size_t)bh * NCH * 4096;
  const u16* tb_l = kl_t + (size_t)bh * NCH * 4096;
  const u16* tb_w = w_t + (size_t)bh * NCH * 4096;

  // Q B-frags from tile-swizzled planes: qrow = qc*64+w*16+c ->
  // tile qc*4+w, row16 = c.
  const int qrow = qc * 64 + w * 16 + c;
  bf16x8 qbh_[2], qbl_[2];
  {
    const u16* qt_h = qhb + (size_t)(qc * 4 + w) * 1024 + c * 64;
    const u16* qt_l = qlb + (size_t)(qc * 4 + w) * 1024 + c * 64;
#pragma unroll
    for (int h = 0; h < 2; ++h) {
      const int off = (h * 32 + g * 8) ^ ((c & 7) << 3);
      qbh_[h] = *(const bf16x8*)(qt_h + off);
      qbl_[h] = *(const bf16x8*)(qt_l + off);
    }
  }

  f32x4 oacc[4];
#pragma unroll
  for (int dt = 0; dt < 4; ++dt) oacc[dt] = (f32x4){0.f, 0.f, 0.f, 0.f};

  const int swc = (c & 7) << 3;
  const int pbase = w * 1024 + c * 64;
  const int so = tid * 8;                     // staging offset (u16 units)

  // prologue: load chunk 0 into staging regs
  u16x8 stg[6];
#pragma unroll
  for (int j = 0; j < 2; ++j) {
    stg[0 + j] = *(const u16x8*)(tb_h + j * 2048 + so);
    stg[2 + j] = *(const u16x8*)(tb_l + j * 2048 + so);
    stg[4 + j] = *(const u16x8*)(tb_w + j * 2048 + so);
  }

  for (int kc = 0; kc < NCH; ++kc) {
    __syncthreads();                          // prior readers of sbuf done
#pragma unroll
    for (int j = 0; j < 2; ++j) {
      *(u16x8*)(sbuf + j * 2048 + so) = stg[0 + j];
      *(u16x8*)(sbuf + 4096 + j * 2048 + so) = stg[2 + j];
      *(u16x8*)(sbuf + 8192 + j * 2048 + so) = stg[4 + j];
    }
    __syncthreads();                          // sbuf ready
    if (kc + 1 < NCH) {                       // T14 prefetch
      const size_t nb = (size_t)(kc + 1) * 4096;
#pragma unroll
      for (int j = 0; j < 2; ++j) {
        stg[0 + j] = *(const u16x8*)(tb_h + nb + j * 2048 + so);
        stg[2 + j] = *(const u16x8*)(tb_l + nb + j * 2048 + so);
        stg[4 + j] = *(const u16x8*)(tb_w + nb + j * 2048 + so);
      }
    }

    const u64 mw = mbits[(size_t)qrow * NCH + kc];

    // QK^T + mask + exp2 -> P (per-wave LDS tile)
#pragma unroll
    for (int kt = 0; kt < 4; ++kt) {
      const int kbase = (16 * kt + c) * 64;
      bf16x8 akh[2], akl[2];
#pragma unroll
      for (int h = 0; h < 2; ++h) {
        const int off = (h * 32 + g * 8) ^ swc;
        akh[h] = *(const bf16x8*)(sbuf + kbase + off);
        akl[h] = *(const bf16x8*)(sbuf + 4096 + kbase + off);
      }
      f32x4 acc = {0.f, 0.f, 0.f, 0.f};
#pragma unroll
      for (int h = 0; h < 2; ++h) {     // IDENTICAL order to passA
        acc = MFMA32(akh[h], qbh_[h], acc);
        acc = MFMA32(akl[h], qbh_[h], acc);
        acc = MFMA32(akh[h], qbl_[h], acc);
      }
      const unsigned nib = (unsigned)(mw >> (kt * 16 + g * 4)) & 0xFu;
      u16 pb[4];
#pragma unroll
      for (int r = 0; r < 4; ++r) {
        const float s = ((nib >> r) & 1) ? MASKED_L2 : acc[r];
        pb[r] = f2bf_rne(EXP2(s));
      }
      *(ushort4*)(p_s + pbase + ((kt * 16 + g * 4) ^ swc)) =
          make_ushort4(pb[0], pb[1], pb[2], pb[3]);
    }

    // PV: oacc[dt] += wT[16dt.., k-slice] * P[k-slice, q]  (2 slices of 32)
#pragma unroll
    for (int s2 = 0; s2 < 2; ++s2) {
      const int koff = (s2 * 32 + g * 8) ^ swc;
      bf16x8 pb8 = *(const bf16x8*)(p_s + pbase + koff);
#pragma unroll
      for (int dt = 0; dt < 4; ++dt) {
        bf16x8 av = *(const bf16x8*)(sbuf + 8192 + (16 * dt + c) * 64 + koff);
        oacc[dt] = MFMA32(av, pb8, oacc[dt]);
      }
    }
  }

  // epilogue: lane (c,g) owns row q = qrow, cols d = 16dt+4g+r
  float* ob = out + ((size_t)bh * S_LEN + qrow) * 64;
#pragma unroll
  for (int dt = 0; dt < 4; ++dt) {
    float4 o = {oacc[dt][0], oacc[dt][1], oacc[dt][2], oacc[dt][3]};
    *(float4*)(ob + dt * 16 + g * 4) = o;
  }
}

// ===========================================================================
// FALLBACK (round-4 proven kernels) — used when ws_size is too small.
// ===========================================================================
__global__ __launch_bounds__(256) void passA_colsum(
    const float* __restrict__ Q, const float* __restrict__ K,
    const u64* __restrict__ mbits, float* __restrict__ il_out) {
  const int tid = threadIdx.x;
  const int lane = tid & 63;
  const int w = tid >> 6;
  const int c = lane & 15;
  const int g = lane >> 4;
  const int kc = blockIdx.x;
  const int bh = blockIdx.y;

  const float* Qb = Q + (size_t)bh * S_LEN * 64;
  const float* Kb = K + (size_t)bh * S_LEN * 64;

  bf16x8 kah[2], kal[2];
  {
    const int krow = kc * 64 + w * 16 + c;
#pragma unroll
    for (int h = 0; h < 2; ++h) {
      const float* src = Kb + (size_t)krow * 64 + h * 32 + g * 8;
      float4 x = *(const float4*)(src);
      float4 y = *(const float4*)(src + 4);
      float xs[8] = {x.x, x.y, x.z, x.w, y.x, y.y, y.z, y.w};
#pragma unroll
      for (int e = 0; e < 8; ++e) {
        u16 hh, ll; bfsplit(xs[e], hh, ll);
        kah[h][e] = (short)hh; kal[h][e] = (short)ll;
      }
    }
  }

  float lp[4] = {0.f, 0.f, 0.f, 0.f};
  const int shift = w * 16 + g * 4;

  for (int qs = 0; qs < S_LEN / 16; ++qs) {
    const int qrow = qs * 16 + c;
    bf16x8 qbh_[2], qbl_[2];
#pragma unroll
    for (int h = 0; h < 2; ++h) {
      const float* src = Qb + (size_t)qrow * 64 + h * 32 + g * 8;
      float4 x = *(const float4*)(src);
      float4 y = *(const float4*)(src + 4);
      float xs[8] = {x.x, x.y, x.z, x.w, y.x, y.y, y.z, y.w};
#pragma unroll
      for (int e = 0; e < 8; ++e) {
        u16 hh, ll; bfsplit(xs[e] * SC, hh, ll);
        qbh_[h][e] = (short)hh; qbl_[h][e] = (short)ll;
      }
    }
    f32x4 acc = {0.f, 0.f, 0.f, 0.f};
#pragma unroll
    for (int h = 0; h < 2; ++h) {
      acc = MFMA32(kah[h], qbh_[h], acc);
      acc = MFMA32(kal[h], qbh_[h], acc);
      acc = MFMA32(kah[h], qbl_[h], acc);
    }
    u64 mw = mbits[(size_t)qrow * NCH + kc];
    unsigned nib = (unsigned)(mw >> shift) & 0xFu;
#pragma unroll
    for (int r = 0; r < 4; ++r) {
      float s = ((nib >> r) & 1) ? MASKED_L2 : acc[r];
      lp[r] += exp2f(s);
    }
  }
#pragma unroll
  for (int off = 1; off < 16; off <<= 1)
#pragma unroll
    for (int r = 0; r < 4; ++r) lp[r] += __shfl_xor(lp[r], off, 64);
  if (c == 0) {
    float4 o = {1.f / lp[0], 1.f / lp[1], 1.f / lp[2], 1.f / lp[3]};
    *(float4*)(il_out + (size_t)bh * S_LEN + kc * 64 + w * 16 + g * 4) = o;
  }
}

__global__ __launch_bounds__(256) void passC_out(
    const float* __restrict__ Q, const float* __restrict__ K,
    const float* __restrict__ V, const u64* __restrict__ mbits,
    const float* __restrict__ il_in, float* __restrict__ out) {
  __shared__ u16 kh_s[4096];
  __shared__ u16 kl_s[4096];
  __shared__ u16 vt_s[4096];
  __shared__ u16 p_s[4096];

  const int tid = threadIdx.x;
  const int lane = tid & 63;
  const int w = tid >> 6;
  const int c = lane & 15;
  const int g = lane >> 4;
  const int qc = blockIdx.x;
  const int bh = blockIdx.y;

  const float* Qb = Q + (size_t)bh * S_LEN * 64;
  const float* Kb = K + (size_t)bh * S_LEN * 64;
  const float* Vb = V + (size_t)bh * S_LEN * 64;

  bf16x8 qbh_[2], qbl_[2];
  {
    const int qrow = qc * 64 + w * 16 + c;
#pragma unroll
    for (int h = 0; h < 2; ++h) {
      const float* src = Qb + (size_t)qrow * 64 + h * 32 + g * 8;
      float4 x = *(const float4*)(src);
      float4 y = *(const float4*)(src + 4);
      float xs[8] = {x.x, x.y, x.z, x.w, y.x, y.y, y.z, y.w};
#pragma unroll
      for (int e = 0; e < 8; ++e) {
        u16 hh, ll; bfsplit(xs[e] * SC, hh, ll);
        qbh_[h][e] = (short)hh; qbl_[h][e] = (short)ll;
      }
    }
  }

  f32x4 oacc[4];
#pragma unroll
  for (int dt = 0; dt < 4; ++dt) oacc[dt] = (f32x4){0.f, 0.f, 0.f, 0.f};

  const int slot = tid & 15, r0 = tid >> 4;
  const int kv = tid & 63, dblk = tid >> 6;
  const int swc = (c & 7) << 3;
  const int pbase = w * 1024 + c * 64;

  for (int kc = 0; kc < NCH; ++kc) {
    __syncthreads();
#pragma unroll
    for (int p = 0; p < 4; ++p) {
      const int row = p * 16 + r0;
      float4 kx = *(const float4*)(Kb + (size_t)(kc * 64 + row) * 64 + slot * 4);
      float xs[4] = {kx.x, kx.y, kx.z, kx.w};
      u16 ha[4], la[4];
#pragma unroll
      for (int e = 0; e < 4; ++e) bfsplit(xs[e], ha[e], la[e]);
      const int idx = row * 64 + ((slot * 4) ^ ((row & 7) << 3));
      *(ushort4*)(kh_s + idx) = make_ushort4(ha[0], ha[1], ha[2], ha[3]);
      *(ushort4*)(kl_s + idx) = make_ushort4(la[0], la[1], la[2], la[3]);
    }
    {
      const float ilk = il_in[(size_t)bh * S_LEN + kc * 64 + kv];
#pragma unroll
      for (int u = 0; u < 4; ++u) {
        float4 vv = *(const float4*)(Vb + (size_t)(kc * 64 + kv) * 64 + dblk * 16 + u * 4);
        float xs[4] = {vv.x, vv.y, vv.z, vv.w};
#pragma unroll
        for (int e = 0; e < 4; ++e) {
          const int d = dblk * 16 + u * 4 + e;
          vt_s[d * 64 + (kv ^ ((d & 7) << 3))] = f2bf_rne(xs[e] * ilk);
        }
      }
    }
    __syncthreads();

    const u64 mw = mbits[(size_t)(qc * 64 + w * 16 + c) * NCH + kc];

#pragma unroll
    for (int kt = 0; kt < 4; ++kt) {
      const int kbase = (16 * kt + c) * 64;
      bf16x8 akh[2], akl[2];
#pragma unroll
      for (int h = 0; h < 2; ++h) {
        const int off = (h * 32 + g * 8) ^ swc;
        akh[h] = *(const bf16x8*)(kh_s + kbase + off);
        akl[h] = *(const bf16x8*)(kl_s + kbase + off);
      }
      f32x4 acc = {0.f, 0.f, 0.f, 0.f};
#pragma unroll
      for (int h = 0; h < 2; ++h) {
        acc = MFMA32(akh[h], qbh_[h], acc);
        acc = MFMA32(akl[h], qbh_[h], acc);
        acc = MFMA32(akh[h], qbl_[h], acc);
      }
      const unsigned nib = (unsigned)(mw >> (kt * 16 + g * 4)) & 0xFu;
      u16 pb[4];
#pragma unroll
      for (int r = 0; r < 4; ++r) {
        const float s = ((nib >> r) & 1) ? MASKED_L2 : acc[r];
        pb[r] = f2bf_rne(exp2f(s));
      }
      *(ushort4*)(p_s + pbase + ((kt * 16 + g * 4) ^ swc)) =
          make_ushort4(pb[0], pb[1], pb[2], pb[3]);
    }
    __syncthreads();

#pragma unroll
    for (int s = 0; s < 2; ++s) {
      const int koff = (s * 32 + 8 * g) ^ swc;
      bf16x8 pb8 = *(const bf16x8*)(p_s + pbase + koff);
#pragma unroll
      for (int dt = 0; dt < 4; ++dt) {
        bf16x8 av = *(const bf16x8*)(vt_s + (16 * dt + c) * 64 + koff);
        oacc[dt] = MFMA32(av, pb8, oacc[dt]);
      }
    }
  }

  float* ob = out + ((size_t)bh * S_LEN + qc * 64 + w * 16 + c) * 64;
#pragma unroll
  for (int dt = 0; dt < 4; ++dt) {
    float4 o = {oacc[dt][0], oacc[dt][1], oacc[dt][2], oacc[dt][3]};
    *(float4*)(ob + dt * 16 + g * 4) = o;
  }
}

extern "C" void kernel_launch(void* const* d_in, const int* in_sizes, int n_in,
                              void* d_out, int out_size, void* d_ws, size_t ws_size,
                              hipStream_t stream) {
  (void)in_sizes; (void)n_in; (void)out_size;
  const float* q = (const float*)d_in[0];
  const float* k = (const float*)d_in[1];
  const float* v = (const float*)d_in[2];
  const int* mask = (const int*)d_in[3];
  float* out = (float*)d_out;

  // ws: mbits(512KB) | part[2][32][2048] f32 (1MB region) | qh|ql (tile-
  // swizzled planes) | kh_t|kl_t|w_t (swizzled tile planes), 8.4MB each
  u64* mbits = (u64*)d_ws;
  float* part = (float*)((char*)d_ws + 524288);
  const size_t PL = (size_t)N_BH * S_LEN * 64;       // 4,194,304 elems/plane
  u16* qh = (u16*)((char*)d_ws + 524288 + 1048576);
  u16* ql = qh + PL;
  u16* kh_t = ql + PL;
  u16* kl_t = kh_t + PL;
  u16* w_t = kl_t + PL;
  const size_t need = 524288 + 1048576 + 5 * PL * sizeof(u16); // 43,515,904

  pack_mask<<<dim3(S_LEN * NCH / 4), 256, 0, stream>>>(mask, mbits);

  if (ws_size >= need) {
    prep_q<<<dim3(1024), 256, 0, stream>>>(q, qh, ql);
    prep_k<<<dim3(NCH, N_BH), 256, 0, stream>>>(k, kh_t, kl_t);
    passA<<<dim3(8, N_BH, 2), 512, 0, stream>>>(qh, ql, kh_t, kl_t, mbits, part);
    prep_w<<<dim3(NCH, N_BH), 256, 0, stream>>>(v, part, w_t);
    passC<<<dim3(NCH, N_BH), 256, 0, stream>>>(qh, ql, kh_t, kl_t, w_t, mbits, out);
  } else {
    float* il = part;            // 256KB, fits
    dim3 grid(NCH, N_BH);
    passA_colsum<<<grid, 256, 0, stream>>>(q, k, mbits, il);
    passC_out<<<grid, 256, 0, stream>>>(q, k, v, mbits, il, out);
  }
}

// Round 9
// 127.467 us; speedup vs baseline: 4.2188x; 1.4050x over previous
//
#include <hip/hip_runtime.h>
#include <math.h>

// B=2, H=16, S=2048, DK=64
#define S_LEN 2048
#define NCH   32          // S/64 chunks
#define N_BH  32

typedef short bf16x8 __attribute__((ext_vector_type(8)));
typedef _Float16 f16x8 __attribute__((ext_vector_type(8)));
typedef float f32x4  __attribute__((ext_vector_type(4)));
typedef unsigned short u16;
typedef unsigned short u16x8 __attribute__((ext_vector_type(8)));
typedef unsigned long long u64;

#define MFMA32(a,b,c) __builtin_amdgcn_mfma_f32_16x16x32_bf16((a),(b),(c),0,0,0)
#define MFMAH(a,b,c)  __builtin_amdgcn_mfma_f32_16x16x32_f16((a),(b),(c),0,0,0)
#define EXP2(x) __builtin_amdgcn_exp2f(x)

// (1/sqrt(64)) * log2(e): scores in log2 units; exp2 = one v_exp_f32.
#define SC        0.18033688011112042f
// masked score in log2 units: exp2(-14) = 6.1e-5 stays fp16-NORMAL (exact
// power of 2). Leakage vs unmasked ~4e-5 relative. A fully-masked column
// degrades to EXACT uniform 1/2048 (l = 2048*2^-14, il = 8, P*il = 2^-11).
#define MASKED_L2 (-14.0f)

__device__ __forceinline__ u16 f2h(float x) {
  union { _Float16 h; u16 u; } v;
  v.h = (_Float16)x;          // RNE
  return v.u;
}
__device__ __forceinline__ u16 f2bf_rne(float x) {
  unsigned u = __float_as_uint(x);
  return (u16)((u + 0x7FFF + ((u >> 16) & 1)) >> 16);
}
__device__ __forceinline__ void bfsplit(float x, u16& h, u16& l) {
  unsigned u = __float_as_uint(x);
  h = (u16)(u >> 16);
  float hf = __uint_as_float(u & 0xFFFF0000u);
  l = f2bf_rne(x - hf);
}

// ---------------------------------------------------------------------------
// pack_mask: word (row, wc) = ballot over k = wc*64 + lane.
// ---------------------------------------------------------------------------
__global__ __launch_bounds__(256) void pack_mask(
    const int* __restrict__ mask, u64* __restrict__ bits) {
  const int word = blockIdx.x * 4 + (threadIdx.x >> 6);
  const int lane = threadIdx.x & 63;
  const int row = word >> 5, wc = word & 31;
  int m = mask[(size_t)row * S_LEN + wc * 64 + lane];
  u64 b = __ballot(m != 0);
  if (lane == 0) bits[word] = b;
}

// ---------------------------------------------------------------------------
// prep_qk: Q*SC -> fp16 plane, K -> fp16 plane, both in the linear swizzled
// layout  plane[row*64 + (col ^ ((row&7)*8))]  that every consumer reads.
// Writes permute only within one 128B line -> still coalesced.
// ---------------------------------------------------------------------------
__global__ __launch_bounds__(256) void prep_qk(
    const float* __restrict__ Q, const float* __restrict__ K,
    u16* __restrict__ qf, u16* __restrict__ kf) {
  const int tid = threadIdx.x;
  const int slot = tid & 15, r0 = tid >> 4;
  const size_t rowbase = (size_t)blockIdx.x * 64;
#pragma unroll
  for (int p = 0; p < 4; ++p) {
    const size_t row = rowbase + p * 16 + r0;
    const size_t dst = row * 64 + ((slot * 4) ^ (((int)row & 7) << 3));
    float4 xq = *(const float4*)(Q + row * 64 + slot * 4);
    *(ushort4*)(qf + dst) = make_ushort4(
        f2h(xq.x * SC), f2h(xq.y * SC), f2h(xq.z * SC), f2h(xq.w * SC));
    float4 xk = *(const float4*)(K + row * 64 + slot * 4);
    *(ushort4*)(kf + dst) = make_ushort4(
        f2h(xk.x), f2h(xk.y), f2h(xk.z), f2h(xk.w));
  }
}

// ---------------------------------------------------------------------------
// prep_w: il[k] = 1/sum(2 partials); wT[d][k] = fp16(il*V[k][d]) as SWIZZLED
// 64x64 tiles [bh][kc][ d*64 + (k ^ ((d&7)*8)) ].
// ---------------------------------------------------------------------------
__global__ __launch_bounds__(256) void prep_w(
    const float* __restrict__ V, const float* __restrict__ part,
    u16* __restrict__ w_t) {
  __shared__ __align__(16) u16 ts[4096];
  const int tid = threadIdx.x;
  const int kc = blockIdx.x, bh = blockIdx.y;
  const int k = tid >> 2, dblk = (tid & 3) * 16;
  const size_t ko = (size_t)bh * S_LEN + kc * 64 + k;
  const float lsum = part[ko] + part[65536 + ko];
  const float ilk = 1.0f / lsum;
  const float* vb = V + ko * 64 + dblk;
#pragma unroll
  for (int u = 0; u < 4; ++u) {
    float4 x = *(const float4*)(vb + u * 4);
    float xs[4] = {x.x, x.y, x.z, x.w};
#pragma unroll
    for (int e = 0; e < 4; ++e) {
      const int d = dblk + u * 4 + e;
      ts[d * 64 + (k ^ ((d & 7) << 3))] = f2h(xs[e] * ilk);
    }
  }
  __syncthreads();
  u16* dst = w_t + ((size_t)bh * NCH + kc) * 4096;
#pragma unroll
  for (int j = 0; j < 2; ++j)
    *(u16x8*)(dst + j * 2048 + tid * 8) = *(const u16x8*)(ts + j * 2048 + tid * 8);
}

// ---------------------------------------------------------------------------
// passA: partial column sums lp[k] = sum_{q in half} exp2(s~[q,k]).
// Grid (8 bx, 32 bh, 2 qp) x 512. Wave owns 32 k (K-frags resident, 16 VGPR).
// 64-row q step-tile staged in LDS (8KB) with the T14 split. fp16 QK:
// 2 MFMA per 16x16 tile. 16 steps.
// ---------------------------------------------------------------------------
__global__ __launch_bounds__(512, 4) void passA(
    const u16* __restrict__ qf, const u16* __restrict__ kf,
    const u64* __restrict__ mbits, float* __restrict__ part) {
  __shared__ __align__(16) u16 qbuf[4096];   // 64 rows x 64 f16, swizzled

  const int tid = threadIdx.x;
  const int lane = tid & 63;
  const int w = tid >> 6;          // 0..7
  const int c = lane & 15;
  const int g = lane >> 4;
  const int bx = blockIdx.x;       // 0..7 (256 k each)
  const int bh = blockIdx.y;
  const int qp = blockIdx.z;       // 0..1 (1024 q each)

  const size_t bh_off = (size_t)bh * S_LEN * 64;
  const int swc = (c & 7) << 3;

  // resident K A-frags (2 x 16-k tiles)
  f16x8 ka[2][2];
#pragma unroll
  for (int t = 0; t < 2; ++t) {
    const int row = bx * 256 + w * 32 + t * 16 + c;
#pragma unroll
    for (int h = 0; h < 2; ++h)
      ka[t][h] = *(const f16x8*)(kf + bh_off + (size_t)row * 64
                                 + ((h * 32 + g * 8) ^ swc));
  }

  u16x8 stg = *(const u16x8*)(qf + bh_off + (size_t)(qp * 1024) * 64 + tid * 8);

  float lp[2][4] = {{0.f, 0.f, 0.f, 0.f}, {0.f, 0.f, 0.f, 0.f}};
  const int word = bx * 4 + (w >> 1);
  const int sh0 = (w & 1) * 32;

  for (int qs = 0; qs < 16; ++qs) {
    __syncthreads();                       // prior readers of qbuf done
    *(u16x8*)(qbuf + tid * 8) = stg;       // commit
    __syncthreads();                       // qbuf ready
    if (qs + 1 < 16)                       // T14: issue next step's loads
      stg = *(const u16x8*)(qf + bh_off
            + (size_t)(qp * 1024 + (qs + 1) * 64) * 64 + tid * 8);

#pragma unroll
    for (int sub = 0; sub < 4; ++sub) {
      f16x8 fh[2];
      const int rb = sub * 1024 + c * 64;
#pragma unroll
      for (int h = 0; h < 2; ++h)
        fh[h] = *(const f16x8*)(qbuf + rb + ((h * 32 + g * 8) ^ swc));
      const int qrow = qp * 1024 + qs * 64 + sub * 16 + c;
      const u64 mw = mbits[(size_t)qrow * NCH + word];
#pragma unroll
      for (int t = 0; t < 2; ++t) {
        f32x4 acc = {0.f, 0.f, 0.f, 0.f};
        acc = MFMAH(ka[t][0], fh[0], acc);  // IDENTICAL order in passC
        acc = MFMAH(ka[t][1], fh[1], acc);
        const unsigned nib = (unsigned)(mw >> (sh0 + t * 16 + g * 4)) & 0xFu;
#pragma unroll
        for (int r = 0; r < 4; ++r) {
          const float s = ((nib >> r) & 1) ? MASKED_L2 : acc[r];
          lp[t][r] += EXP2(s);
        }
      }
    }
  }

  // reduce over the 16 c-lanes of each g-group
#pragma unroll
  for (int off = 1; off < 16; off <<= 1)
#pragma unroll
    for (int t = 0; t < 2; ++t)
#pragma unroll
      for (int r = 0; r < 4; ++r) lp[t][r] += __shfl_xor(lp[t][r], off, 64);
  if (c == 0) {
#pragma unroll
    for (int t = 0; t < 2; ++t) {
      float4 o = {lp[t][0], lp[t][1], lp[t][2], lp[t][3]};
      *(float4*)(part + (size_t)qp * 65536 + (size_t)bh * S_LEN
                 + bx * 256 + w * 32 + t * 16 + g * 4) = o;
    }
  }
}

// ---------------------------------------------------------------------------
// passC: out[q,d] = sum_k exp2(s~[q,k]) * wT[d,k]   (all fp16 MFMA).
// 4 waves share an LDS-staged chunk {kf|wT} (16KB, pure 16B-copy staging,
// T14 prefetch). Per-wave P tile (fp16) in LDS. 16 MFMA / chunk / wave.
// ---------------------------------------------------------------------------
__global__ __launch_bounds__(256, 4) void passC(
    const u16* __restrict__ qf, const u16* __restrict__ kf,
    const u16* __restrict__ w_t, const u64* __restrict__ mbits,
    float* __restrict__ out) {
  __shared__ __align__(16) u16 sbuf[8192];    // [kf:4096 | wT:4096]
  __shared__ __align__(16) u16 p_s[4096];     // per-wave [16 q][64 k], swizzled

  const int tid = threadIdx.x;
  const int lane = tid & 63;
  const int w = tid >> 6;
  const int c = lane & 15;
  const int g = lane >> 4;
  const int qc = blockIdx.x;
  const int bh = blockIdx.y;

  const size_t bh_off = (size_t)bh * S_LEN * 64;
  const u16* tb_k = kf + bh_off;
  const u16* tb_w = w_t + (size_t)bh * NCH * 4096;
  const int swc = (c & 7) << 3;

  // Q B-frags from the swizzled plane (resident for the whole block)
  const int qrow = qc * 64 + w * 16 + c;
  f16x8 qb_[2];
#pragma unroll
  for (int h = 0; h < 2; ++h)
    qb_[h] = *(const f16x8*)(qf + bh_off + (size_t)qrow * 64
                             + ((h * 32 + g * 8) ^ swc));

  f32x4 oacc[4];
#pragma unroll
  for (int dt = 0; dt < 4; ++dt) oacc[dt] = (f32x4){0.f, 0.f, 0.f, 0.f};

  const int pbase = w * 1024 + c * 64;
  const int so = tid * 8;                     // staging offset (u16 units)

  // prologue: load chunk 0 into staging regs
  u16x8 stg[4];
#pragma unroll
  for (int j = 0; j < 2; ++j) {
    stg[0 + j] = *(const u16x8*)(tb_k + j * 2048 + so);
    stg[2 + j] = *(const u16x8*)(tb_w + j * 2048 + so);
  }

  for (int kc = 0; kc < NCH; ++kc) {
    __syncthreads();                          // prior readers of sbuf done
#pragma unroll
    for (int j = 0; j < 2; ++j) {
      *(u16x8*)(sbuf + j * 2048 + so) = stg[0 + j];
      *(u16x8*)(sbuf + 4096 + j * 2048 + so) = stg[2 + j];
    }
    __syncthreads();                          // sbuf ready
    if (kc + 1 < NCH) {                       // T14 prefetch
      const size_t nb = (size_t)(kc + 1) * 4096;
#pragma unroll
      for (int j = 0; j < 2; ++j) {
        stg[0 + j] = *(const u16x8*)(tb_k + nb + j * 2048 + so);
        stg[2 + j] = *(const u16x8*)(tb_w + nb + j * 2048 + so);
      }
    }

    const u64 mw = mbits[(size_t)qrow * NCH + kc];

    // QK^T + mask + exp2 -> P (per-wave LDS tile, fp16)
#pragma unroll
    for (int kt = 0; kt < 4; ++kt) {
      const int kbase = (16 * kt + c) * 64;
      f16x8 ak0 = *(const f16x8*)(sbuf + kbase + ((0 * 32 + g * 8) ^ swc));
      f16x8 ak1 = *(const f16x8*)(sbuf + kbase + ((1 * 32 + g * 8) ^ swc));
      f32x4 acc = {0.f, 0.f, 0.f, 0.f};
      acc = MFMAH(ak0, qb_[0], acc);          // IDENTICAL order to passA
      acc = MFMAH(ak1, qb_[1], acc);
      const unsigned nib = (unsigned)(mw >> (kt * 16 + g * 4)) & 0xFu;
      u16 pb[4];
#pragma unroll
      for (int r = 0; r < 4; ++r) {
        const float s = ((nib >> r) & 1) ? MASKED_L2 : acc[r];
        pb[r] = f2h(EXP2(s));
      }
      *(ushort4*)(p_s + pbase + ((kt * 16 + g * 4) ^ swc)) =
          make_ushort4(pb[0], pb[1], pb[2], pb[3]);
    }

    // PV: oacc[dt] += wT[16dt.., k-slice] * P[k-slice, q]  (2 slices of 32)
#pragma unroll
    for (int s2 = 0; s2 < 2; ++s2) {
      const int koff = (s2 * 32 + g * 8) ^ swc;
      f16x8 pb8 = *(const f16x8*)(p_s + pbase + koff);
#pragma unroll
      for (int dt = 0; dt < 4; ++dt) {
        f16x8 av = *(const f16x8*)(sbuf + 4096 + (16 * dt + c) * 64 + koff);
        oacc[dt] = MFMAH(av, pb8, oacc[dt]);
      }
    }
  }

  // epilogue: lane (c,g) owns row q = qrow, cols d = 16dt+4g+r
  float* ob = out + (bh_off + (size_t)qrow * 64);
#pragma unroll
  for (int dt = 0; dt < 4; ++dt) {
    float4 o = {oacc[dt][0], oacc[dt][1], oacc[dt][2], oacc[dt][3]};
    *(float4*)(ob + dt * 16 + g * 4) = o;
  }
}

// ===========================================================================
// FALLBACK (round-4 proven kernels) — used when ws_size is too small.
// ===========================================================================
__global__ __launch_bounds__(256) void passA_colsum(
    const float* __restrict__ Q, const float* __restrict__ K,
    const u64* __restrict__ mbits, float* __restrict__ il_out) {
  const int tid = threadIdx.x;
  const int lane = tid & 63;
  const int w = tid >> 6;
  const int c = lane & 15;
  const int g = lane >> 4;
  const int kc = blockIdx.x;
  const int bh = blockIdx.y;

  const float* Qb = Q + (size_t)bh * S_LEN * 64;
  const float* Kb = K + (size_t)bh * S_LEN * 64;

  bf16x8 kah[2], kal[2];
  {
    const int krow = kc * 64 + w * 16 + c;
#pragma unroll
    for (int h = 0; h < 2; ++h) {
      const float* src = Kb + (size_t)krow * 64 + h * 32 + g * 8;
      float4 x = *(const float4*)(src);
      float4 y = *(const float4*)(src + 4);
      float xs[8] = {x.x, x.y, x.z, x.w, y.x, y.y, y.z, y.w};
#pragma unroll
      for (int e = 0; e < 8; ++e) {
        u16 hh, ll; bfsplit(xs[e], hh, ll);
        kah[h][e] = (short)hh; kal[h][e] = (short)ll;
      }
    }
  }

  float lp[4] = {0.f, 0.f, 0.f, 0.f};
  const int shift = w * 16 + g * 4;

  for (int qs = 0; qs < S_LEN / 16; ++qs) {
    const int qrow = qs * 16 + c;
    bf16x8 qbh_[2], qbl_[2];
#pragma unroll
    for (int h = 0; h < 2; ++h) {
      const float* src = Qb + (size_t)qrow * 64 + h * 32 + g * 8;
      float4 x = *(const float4*)(src);
      float4 y = *(const float4*)(src + 4);
      float xs[8] = {x.x, x.y, x.z, x.w, y.x, y.y, y.z, y.w};
#pragma unroll
      for (int e = 0; e < 8; ++e) {
        u16 hh, ll; bfsplit(xs[e] * SC, hh, ll);
        qbh_[h][e] = (short)hh; qbl_[h][e] = (short)ll;
      }
    }
    f32x4 acc = {0.f, 0.f, 0.f, 0.f};
#pragma unroll
    for (int h = 0; h < 2; ++h) {
      acc = MFMA32(kah[h], qbh_[h], acc);
      acc = MFMA32(kal[h], qbh_[h], acc);
      acc = MFMA32(kah[h], qbl_[h], acc);
    }
    u64 mw = mbits[(size_t)qrow * NCH + kc];
    unsigned nib = (unsigned)(mw >> shift) & 0xFu;
#pragma unroll
    for (int r = 0; r < 4; ++r) {
      float s = ((nib >> r) & 1) ? MASKED_L2 : acc[r];
      lp[r] += exp2f(s);
    }
  }
#pragma unroll
  for (int off = 1; off < 16; off <<= 1)
#pragma unroll
    for (int r = 0; r < 4; ++r) lp[r] += __shfl_xor(lp[r], off, 64);
  if (c == 0) {
    float4 o = {1.f / lp[0], 1.f / lp[1], 1.f / lp[2], 1.f / lp[3]};
    *(float4*)(il_out + (size_t)bh * S_LEN + kc * 64 + w * 16 + g * 4) = o;
  }
}

__global__ __launch_bounds__(256) void passC_out(
    const float* __restrict__ Q, const float* __restrict__ K,
    const float* __restrict__ V, const u64* __restrict__ mbits,
    const float* __restrict__ il_in, float* __restrict__ out) {
  __shared__ u16 kh_s[4096];
  __shared__ u16 kl_s[4096];
  __shared__ u16 vt_s[4096];
  __shared__ u16 p_s[4096];

  const int tid = threadIdx.x;
  const int lane = tid & 63;
  const int w = tid >> 6;
  const int c = lane & 15;
  const int g = lane >> 4;
  const int qc = blockIdx.x;
  const int bh = blockIdx.y;

  const float* Qb = Q + (size_t)bh * S_LEN * 64;
  const float* Kb = K + (size_t)bh * S_LEN * 64;
  const float* Vb = V + (size_t)bh * S_LEN * 64;

  bf16x8 qbh_[2], qbl_[2];
  {
    const int qrow = qc * 64 + w * 16 + c;
#pragma unroll
    for (int h = 0; h < 2; ++h) {
      const float* src = Qb + (size_t)qrow * 64 + h * 32 + g * 8;
      float4 x = *(const float4*)(src);
      float4 y = *(const float4*)(src + 4);
      float xs[8] = {x.x, x.y, x.z, x.w, y.x, y.y, y.z, y.w};
#pragma unroll
      for (int e = 0; e < 8; ++e) {
        u16 hh, ll; bfsplit(xs[e] * SC, hh, ll);
        qbh_[h][e] = (short)hh; qbl_[h][e] = (short)ll;
      }
    }
  }

  f32x4 oacc[4];
#pragma unroll
  for (int dt = 0; dt < 4; ++dt) oacc[dt] = (f32x4){0.f, 0.f, 0.f, 0.f};

  const int slot = tid & 15, r0 = tid >> 4;
  const int kv = tid & 63, dblk = tid >> 6;
  const int swc = (c & 7) << 3;
  const int pbase = w * 1024 + c * 64;

  for (int kc = 0; kc < NCH; ++kc) {
    __syncthreads();
#pragma unroll
    for (int p = 0; p < 4; ++p) {
      const int row = p * 16 + r0;
      float4 kx = *(const float4*)(Kb + (size_t)(kc * 64 + row) * 64 + slot * 4);
      float xs[4] = {kx.x, kx.y, kx.z, kx.w};
      u16 ha[4], la[4];
#pragma unroll
      for (int e = 0; e < 4; ++e) bfsplit(xs[e], ha[e], la[e]);
      const int idx = row * 64 + ((slot * 4) ^ ((row & 7) << 3));
      *(ushort4*)(kh_s + idx) = make_ushort4(ha[0], ha[1], ha[2], ha[3]);
      *(ushort4*)(kl_s + idx) = make_ushort4(la[0], la[1], la[2], la[3]);
    }
    {
      const float ilk = il_in[(size_t)bh * S_LEN + kc * 64 + kv];
#pragma unroll
      for (int u = 0; u < 4; ++u) {
        float4 vv = *(const float4*)(Vb + (size_t)(kc * 64 + kv) * 64 + dblk * 16 + u * 4);
        float xs[4] = {vv.x, vv.y, vv.z, vv.w};
#pragma unroll
        for (int e = 0; e < 4; ++e) {
          const int d = dblk * 16 + u * 4 + e;
          vt_s[d * 64 + (kv ^ ((d & 7) << 3))] = f2bf_rne(xs[e] * ilk);
        }
      }
    }
    __syncthreads();

    const u64 mw = mbits[(size_t)(qc * 64 + w * 16 + c) * NCH + kc];

#pragma unroll
    for (int kt = 0; kt < 4; ++kt) {
      const int kbase = (16 * kt + c) * 64;
      bf16x8 akh[2], akl[2];
#pragma unroll
      for (int h = 0; h < 2; ++h) {
        const int off = (h * 32 + g * 8) ^ swc;
        akh[h] = *(const bf16x8*)(kh_s + kbase + off);
        akl[h] = *(const bf16x8*)(kl_s + kbase + off);
      }
      f32x4 acc = {0.f, 0.f, 0.f, 0.f};
#pragma unroll
      for (int h = 0; h < 2; ++h) {
        acc = MFMA32(akh[h], qbh_[h], acc);
        acc = MFMA32(akl[h], qbh_[h], acc);
        acc = MFMA32(akh[h], qbl_[h], acc);
      }
      const unsigned nib = (unsigned)(mw >> (kt * 16 + g * 4)) & 0xFu;
      u16 pb[4];
#pragma unroll
      for (int r = 0; r < 4; ++r) {
        const float s = ((nib >> r) & 1) ? MASKED_L2 : acc[r];
        pb[r] = f2bf_rne(exp2f(s));
      }
      *(ushort4*)(p_s + pbase + ((kt * 16 + g * 4) ^ swc)) =
          make_ushort4(pb[0], pb[1], pb[2], pb[3]);
    }
    __syncthreads();

#pragma unroll
    for (int s = 0; s < 2; ++s) {
      const int koff = (s * 32 + 8 * g) ^ swc;
      bf16x8 pb8 = *(const bf16x8*)(p_s + pbase + koff);
#pragma unroll
      for (int dt = 0; dt < 4; ++dt) {
        bf16x8 av = *(const bf16x8*)(vt_s + (16 * dt + c) * 64 + koff);
        oacc[dt] = MFMA32(av, pb8, oacc[dt]);
      }
    }
  }

  float* ob = out + ((size_t)bh * S_LEN + qc * 64 + w * 16 + c) * 64;
#pragma unroll
  for (int dt = 0; dt < 4; ++dt) {
    float4 o = {oacc[dt][0], oacc[dt][1], oacc[dt][2], oacc[dt][3]};
    *(float4*)(ob + dt * 16 + g * 4) = o;
  }
}

extern "C" void kernel_launch(void* const* d_in, const int* in_sizes, int n_in,
                              void* d_out, int out_size, void* d_ws, size_t ws_size,
                              hipStream_t stream) {
  (void)in_sizes; (void)n_in; (void)out_size;
  const float* q = (const float*)d_in[0];
  const float* k = (const float*)d_in[1];
  const float* v = (const float*)d_in[2];
  const int* mask = (const int*)d_in[3];
  float* out = (float*)d_out;

  // ws: mbits(512KB) | part[2][32][2048] f32 (1MB region) | qf | kf | w_t
  // (fp16 planes, 8.4MB each)
  u64* mbits = (u64*)d_ws;
  float* part = (float*)((char*)d_ws + 524288);
  const size_t PL = (size_t)N_BH * S_LEN * 64;       // 4,194,304 elems/plane
  u16* qf = (u16*)((char*)d_ws + 524288 + 1048576);
  u16* kf = qf + PL;
  u16* w_t = kf + PL;
  const size_t need = 524288 + 1048576 + 3 * PL * sizeof(u16); // 26,738,688

  pack_mask<<<dim3(S_LEN * NCH / 4), 256, 0, stream>>>(mask, mbits);

  if (ws_size >= need) {
    prep_qk<<<dim3(1024), 256, 0, stream>>>(q, k, qf, kf);
    passA<<<dim3(8, N_BH, 2), 512, 0, stream>>>(qf, kf, mbits, part);
    prep_w<<<dim3(NCH, N_BH), 256, 0, stream>>>(v, part, w_t);
    passC<<<dim3(NCH, N_BH), 256, 0, stream>>>(qf, kf, w_t, mbits, out);
  } else {
    float* il = part;            // 256KB, fits
    dim3 grid(NCH, N_BH);
    passA_colsum<<<grid, 256, 0, stream>>>(q, k, mbits, il);
    passC_out<<<grid, 256, 0, stream>>>(q, k, v, mbits, il, out);
  }
}